// Round 3
// baseline (2282.245 us; speedup 1.0000x reference)
//
#include <hip/hip_runtime.h>
#include <hip/hip_bf16.h>

// Problem constants (fixed by the reference's setup_inputs)
#define N_ITEM 80000
#define N_USER 20000
#define NN     100000   // N_ITEM + N_USER
#define NE     1000000  // edges
// dims: feat=64, user=128, id=64

typedef __hip_bfloat16 bf16;

__device__ __forceinline__ float b2f(bf16 v) { return __bfloat162float(v); }
__device__ __forceinline__ bf16  f2b(float v) { return __float2bfloat16(v); }
__device__ __forceinline__ float leaky(float v) { return v >= 0.f ? v : 0.01f * v; }

// dtype-adaptive load/store: T is the storage type of harness buffers
template<typename T>
__device__ __forceinline__ float ldT(const void* p, size_t i);
template<> __device__ __forceinline__ float ldT<float>(const void* p, size_t i) {
    return ((const float*)p)[i];
}
template<> __device__ __forceinline__ float ldT<bf16>(const void* p, size_t i) {
    return b2f(((const bf16*)p)[i]);
}
template<typename T>
__device__ __forceinline__ void stT(void* p, size_t i, float v);
template<> __device__ __forceinline__ void stT<float>(void* p, size_t i, float v) {
    ((float*)p)[i] = v;
}
template<> __device__ __forceinline__ void stT<bf16>(void* p, size_t i, float v) {
    ((bf16*)p)[i] = f2b(v);
}

// full 64-lane wave sum
__device__ __forceinline__ float wred(float v) {
    for (int o = 32; o; o >>= 1) v += __shfl_xor(v, o, 64);
    return v;
}

// order-preserving float -> uint key (for atomicMax on signed floats)
__device__ __forceinline__ unsigned fkey(float f) {
    unsigned b = __float_as_uint(f);
    return (b & 0x80000000u) ? ~b : (b | 0x80000000u);
}
__device__ __forceinline__ float funkey(unsigned k) {
    unsigned b = (k & 0x80000000u) ? (k & 0x7FFFFFFFu) : ~k;
    return __uint_as_float(b);
}

// ---- storage-dtype detection ----
// Scan first 4096 uint16 words of `features`. bf16-rounded N(0,1) data has
// exponent field in ~[118,129], never 0x00/0xFF. If the buffer is really
// float32, even-index words are low mantissa halves (uniform bits) -> ~32
// expected hits of exp==0x00/0xFF. Any hit => storage is f32 (mode=1).
__global__ void k_detect(const unsigned short* __restrict__ w, int* __restrict__ mode) {
    __shared__ int cnt[256];
    int bad = 0;
    for (int i = threadIdx.x; i < 4096; i += 256) {
        unsigned e = (w[i] >> 7) & 0xFFu;
        bad += (e == 0u || e == 0xFFu) ? 1 : 0;
    }
    cnt[threadIdx.x] = bad;
    __syncthreads();
    if (threadIdx.x == 0) {
        int t = 0;
        for (int k = 0; k < 256; k++) t += cnt[k];
        mode[0] = (t > 0) ? 1 : 0;   // 1 = float32 storage, 0 = bf16 storage
    }
}

// ---- degree over src (shared by both layers) ----
__global__ void k_deg(const int* __restrict__ src, int* __restrict__ deg) {
    int e = blockIdx.x * blockDim.x + threadIdx.x;
    if (e < NE) atomicAdd(&deg[src[e]], 1);
}

// ---- item rows: normalize(features) -> x[0:80000] ----
template<typename T>
__device__ __forceinline__ void prep_items_body(const void* feat, float* x) {
    int i = blockIdx.x * 4 + (threadIdx.x >> 6);
    int j = threadIdx.x & 63;
    if (i >= N_ITEM) return;
    float v = ldT<T>(feat, (size_t)i * 64 + j);
    float ss = wred(v * v);
    float inv = 1.f / fmaxf(sqrtf(ss), 1e-12f);
    x[(size_t)i * 64 + j] = v * inv;
}
__global__ void k_prep_items(const void* feat, float* x, const int* mode) {
    if (*mode) prep_items_body<float>(feat, x);
    else       prep_items_body<bf16>(feat, x);
}

// ---- user rows: normalize(tanh(uf @ W.T + b)) -> x[80000:100000] ----
template<typename T>
__device__ __forceinline__ void prep_users_body(const void* uf, const void* w,
                                                const void* b, float* x) {
    int u = blockIdx.x * 4 + (threadIdx.x >> 6);
    int j = threadIdx.x & 63;
    if (u >= N_USER) return;
    size_t ub = (size_t)u * 128;
    float acc = ldT<T>(b, j);
    #pragma unroll 8
    for (int k = 0; k < 128; k++)
        acc += ldT<T>(uf, ub + k) * ldT<T>(w, (size_t)j * 128 + k);
    float v = tanhf(acc);
    float ss = wred(v * v);
    float inv = 1.f / fmaxf(sqrtf(ss), 1e-12f);
    x[(size_t)(N_ITEM + u) * 64 + j] = v * inv;
}
__global__ void k_prep_users(const void* uf, const void* w, const void* b,
                             float* x, const int* mode) {
    if (*mode) prep_users_body<float>(uf, w, b, x);
    else       prep_users_body<bf16>(uf, w, b, x);
}

// ---- xw = xin @ W (out_j = sum_k x_k * W[k*64+j]) ----
template<typename T>
__device__ __forceinline__ void xw_body(const float* xin, const void* W, float* xw) {
    int i = blockIdx.x * 4 + (threadIdx.x >> 6);
    int j = threadIdx.x & 63;
    if (i >= NN) return;
    float xv = xin[(size_t)i * 64 + j];
    float acc = 0.f;
    #pragma unroll
    for (int k = 0; k < 64; k++)
        acc += __shfl(xv, k, 64) * ldT<T>(W, (size_t)k * 64 + j);
    xw[(size_t)i * 64 + j] = acc;
}
__global__ void k_xw(const float* xin, const void* W, float* xw, const int* mode) {
    if (*mode) xw_body<float>(xin, W, xw);
    else       xw_body<bf16>(xin, W, xw);
}

// ---- edge pass 1: inner product, gate, logit; segment-max over dst ----
__global__ void k_edge1(const int* __restrict__ src, const int* __restrict__ dst,
                        const float* __restrict__ xw, const int* __restrict__ deg,
                        float* __restrict__ elog, unsigned* __restrict__ mkey) {
    int e = blockIdx.x * 4 + (threadIdx.x >> 6);
    if (e >= NE) return;
    int lane = threadIdx.x & 63;
    int s = src[e], d = dst[e];
    float a = xw[(size_t)s * 64 + lane];
    float c = xw[(size_t)d * 64 + lane];
    float inner = wred(a * c);
    if (lane == 0) {
        float dv = rsqrtf((float)deg[s]);
        float gate = 1.f / (1.f + expf(-dv * inner));
        float logit = inner * gate;
        elog[e] = logit;
        atomicMax(&mkey[d], fkey(logit));
    }
}

// ---- edge pass 2: e = exp(logit - m[dst]); segment-sum z ----
__global__ void k_edge2(const int* __restrict__ dst, const unsigned* __restrict__ mkey,
                        float* __restrict__ elog, float* __restrict__ z) {
    int e = blockIdx.x * blockDim.x + threadIdx.x;
    if (e >= NE) return;
    int d = dst[e];
    float m = funkey(mkey[d]);          // every d here received >=1 atomicMax
    float ev = expf(elog[e] - m);
    elog[e] = ev;                       // in-place: now holds exp value
    atomicAdd(&z[d], ev);
}

// ---- edge pass 3: scatter msg = xw[src] * attn into hacc[dst] ----
__global__ void k_edge3(const int* __restrict__ src, const int* __restrict__ dst,
                        const float* __restrict__ xw, const float* __restrict__ elog,
                        const float* __restrict__ z, float* __restrict__ hacc) {
    int e = blockIdx.x * 4 + (threadIdx.x >> 6);
    if (e >= NE) return;
    int lane = threadIdx.x & 63;
    int s = src[e], d = dst[e];
    float attn = elog[e] / (z[d] + 1e-16f);
    float xs = xw[(size_t)s * 64 + lane];
    atomicAdd(&hacc[(size_t)d * 64 + lane], xs * attn);
}

// ---- epilogue: x_next = leaky(leaky(h)@g.T + gb + leaky(x@lin.T + lb) + id) ----
template<typename T>
__device__ __forceinline__ void combine_body(const float* xin, const float* hacc,
                                             const void* gw, const void* gb,
                                             const void* lw, const void* lb,
                                             const void* id_emb,
                                             float* xnext, void* out, int off) {
    int i = blockIdx.x * 4 + (threadIdx.x >> 6);
    int j = threadIdx.x & 63;
    if (i >= NN) return;
    float hv = leaky(hacc[(size_t)i * 64 + j]);
    float xv = xin[(size_t)i * 64 + j];
    float accg = 0.f, accl = 0.f;
    #pragma unroll
    for (int k = 0; k < 64; k++) {
        float hk = __shfl(hv, k, 64);
        float xk = __shfl(xv, k, 64);
        accg += hk * ldT<T>(gw, (size_t)j * 64 + k);   // h @ g.T
        accl += xk * ldT<T>(lw, (size_t)j * 64 + k);   // x @ lin.T
    }
    float xhat = leaky(accl + ldT<T>(lb, j)) + ldT<T>(id_emb, (size_t)i * 64 + j);
    float xn = leaky(accg + ldT<T>(gb, j) + xhat);
    xnext[(size_t)i * 64 + j] = xn;
    stT<T>(out, (size_t)i * 128 + off + j, xn);
}
__global__ void k_combine(const float* xin, const float* hacc,
                          const void* gw, const void* gb,
                          const void* lw, const void* lb, const void* id_emb,
                          float* xnext, void* out, int off, const int* mode) {
    if (*mode) combine_body<float>(xin, hacc, gw, gb, lw, lb, id_emb, xnext, out, off);
    else       combine_body<bf16>(xin, hacc, gw, gb, lw, lb, id_emb, xnext, out, off);
}

static void run_layer(const int* src, const int* dst, const int* deg,
                      const float* xin, const void* gatw,
                      const void* lw, const void* lb,
                      const void* gw, const void* gb,
                      const void* id_emb,
                      float* xwbuf,      // also receives xnext (xw dead by then)
                      float* hacc, float* elog, unsigned* mkey, float* z,
                      void* out, int off, const int* mode, hipStream_t stream) {
    k_xw<<<(NN + 3) / 4, 256, 0, stream>>>(xin, gatw, xwbuf, mode);
    hipMemsetAsync(mkey, 0, NN * 4, stream);   // key 0 < every finite key
    hipMemsetAsync(z, 0, NN * 4, stream);
    hipMemsetAsync(hacc, 0, (size_t)NN * 64 * 4, stream);
    k_edge1<<<(NE + 3) / 4, 256, 0, stream>>>(src, dst, xwbuf, deg, elog, mkey);
    k_edge2<<<(NE + 255) / 256, 256, 0, stream>>>(dst, mkey, elog, z);  // FIX: was NE/256, dropped 64 edges
    k_edge3<<<(NE + 3) / 4, 256, 0, stream>>>(src, dst, xwbuf, elog, z, hacc);
    k_combine<<<(NN + 3) / 4, 256, 0, stream>>>(xin, hacc, gw, gb, lw, lb, id_emb,
                                                xwbuf, out, off, mode);
}

extern "C" void kernel_launch(void* const* d_in, const int* in_sizes, int n_in,
                              void* d_out, int out_size, void* d_ws, size_t ws_size,
                              hipStream_t stream) {
    const void* feat   = d_in[0];
    const void* uf     = d_in[1];
    const void* id_emb = d_in[2];
    const void* umw    = d_in[3];
    const void* umb    = d_in[4];
    const void* gat1   = d_in[5];
    const void* lin1w  = d_in[6];
    const void* lin1b  = d_in[7];
    const void* g1w    = d_in[8];
    const void* g1b    = d_in[9];
    const void* gat2   = d_in[10];
    const void* lin2w  = d_in[11];
    const void* lin2b  = d_in[12];
    const void* g2w    = d_in[13];
    const void* g2b    = d_in[14];
    const int*  ei     = (const int*)d_in[15];
    const int* src = ei;
    const int* dst = ei + NE;

    // workspace layout: small arrays first, then 3 rotating node buffers (~82 MB)
    int*      mode = (int*)d_ws;                       // 16 B slot
    int*      deg  = (int*)((char*)d_ws + 16);
    unsigned* mkey = (unsigned*)(deg + NN);
    float*    z    = (float*)(mkey + NN);
    float*    elog = z + NN;
    float*    buf0 = elog + NE;                        // x
    float*    buf1 = buf0 + (size_t)NN * 64;           // xw1 / x1
    float*    buf2 = buf1 + (size_t)NN * 64;           // hacc

    k_detect<<<1, 256, 0, stream>>>((const unsigned short*)feat, mode);
    hipMemsetAsync(deg, 0, NN * 4, stream);
    k_deg<<<(NE + 255) / 256, 256, 0, stream>>>(src, deg);
    k_prep_items<<<(N_ITEM + 3) / 4, 256, 0, stream>>>(feat, buf0, mode);
    k_prep_users<<<(N_USER + 3) / 4, 256, 0, stream>>>(uf, umw, umb, buf0, mode);

    // hop 1: buf0 -> buf1 (out cols 0..63)
    run_layer(src, dst, deg, buf0, gat1, lin1w, lin1b, g1w, g1b, id_emb,
              buf1, buf2, elog, mkey, z, d_out, 0, mode, stream);
    // hop 2: buf1 -> buf0 (out cols 64..127)
    run_layer(src, dst, deg, buf1, gat2, lin2w, lin2b, g2w, g2b, id_emb,
              buf0, buf2, elog, mkey, z, d_out, 64, mode, stream);
}

// Round 4
// 1748.340 us; speedup vs baseline: 1.3054x; 1.3054x over previous
//
#include <hip/hip_runtime.h>
#include <hip/hip_bf16.h>

// Problem constants (fixed by the reference's setup_inputs)
#define N_ITEM 80000
#define N_USER 20000
#define NN     100000   // N_ITEM + N_USER
#define NE     1000000  // edges
// dims: feat=64, user=128, id=64

typedef __hip_bfloat16 bf16;

__device__ __forceinline__ float b2f(bf16 v) { return __bfloat162float(v); }
__device__ __forceinline__ bf16  f2b(float v) { return __float2bfloat16(v); }
__device__ __forceinline__ float leaky(float v) { return v >= 0.f ? v : 0.01f * v; }

// dtype-adaptive load/store: T is the storage type of harness buffers
template<typename T>
__device__ __forceinline__ float ldT(const void* p, size_t i);
template<> __device__ __forceinline__ float ldT<float>(const void* p, size_t i) {
    return ((const float*)p)[i];
}
template<> __device__ __forceinline__ float ldT<bf16>(const void* p, size_t i) {
    return b2f(((const bf16*)p)[i]);
}
template<typename T>
__device__ __forceinline__ void stT(void* p, size_t i, float v);
template<> __device__ __forceinline__ void stT<float>(void* p, size_t i, float v) {
    ((float*)p)[i] = v;
}
template<> __device__ __forceinline__ void stT<bf16>(void* p, size_t i, float v) {
    ((bf16*)p)[i] = f2b(v);
}

// full 64-lane wave sum
__device__ __forceinline__ float wred(float v) {
    for (int o = 32; o; o >>= 1) v += __shfl_xor(v, o, 64);
    return v;
}

// order-preserving float -> uint key (for atomicMax on signed floats)
__device__ __forceinline__ unsigned fkey(float f) {
    unsigned b = __float_as_uint(f);
    return (b & 0x80000000u) ? ~b : (b | 0x80000000u);
}
__device__ __forceinline__ float funkey(unsigned k) {
    unsigned b = (k & 0x80000000u) ? (k & 0x7FFFFFFFu) : ~k;
    return __uint_as_float(b);
}

// ---- storage-dtype detection (bf16 vs f32 harness buffers) ----
__global__ void k_detect(const unsigned short* __restrict__ w, int* __restrict__ mode) {
    __shared__ int cnt[256];
    int bad = 0;
    for (int i = threadIdx.x; i < 4096; i += 256) {
        unsigned e = (w[i] >> 7) & 0xFFu;
        bad += (e == 0u || e == 0xFFu) ? 1 : 0;
    }
    cnt[threadIdx.x] = bad;
    __syncthreads();
    if (threadIdx.x == 0) {
        int t = 0;
        for (int k = 0; k < 256; k++) t += cnt[k];
        mode[0] = (t > 0) ? 1 : 0;   // 1 = float32 storage, 0 = bf16 storage
    }
}

// ---- transpose + f32-promote the row-major weights that would otherwise be
//      read with stride-64/128 gathers (the round-3 k_combine bottleneck) ----
// umwT[k*64+j] = umw[j*128+k]  (j<64, k<128)
// wT[m][k*64+j] = w_m[j*64+k]  for m in {lw1, gw1, lw2, gw2}
__global__ void k_prep_w(const void* umw, const void* lw1, const void* gw1,
                         const void* lw2, const void* gw2,
                         float* umwT, float* wT, const int* mode) {
    int t = blockIdx.x * 256 + threadIdx.x;   // 0 .. 24575
    bool f32m = (*mode != 0);
    if (t < 8192) {
        int j = t >> 7, k = t & 127;
        float v = f32m ? ldT<float>(umw, t) : ldT<bf16>(umw, t);
        umwT[k * 64 + j] = v;
    } else {
        int u = t - 8192;
        int m = u >> 12;          // 0..3
        int r = u & 4095;
        int j = r >> 6, k = r & 63;
        const void* srcp = (m == 0) ? lw1 : (m == 1) ? gw1 : (m == 2) ? lw2 : gw2;
        float v = f32m ? ldT<float>(srcp, r) : ldT<bf16>(srcp, r);
        wT[m * 4096 + k * 64 + j] = v;
    }
}

// ---- degree over src (shared by both layers) ----
__global__ void k_deg(const int* __restrict__ src, int* __restrict__ deg) {
    int e = blockIdx.x * blockDim.x + threadIdx.x;
    if (e < NE) atomicAdd(&deg[src[e]], 1);
}

// ---- item rows: normalize(features) -> x[0:80000] ----
template<typename T>
__device__ __forceinline__ void prep_items_body(const void* feat, float* x) {
    int i = blockIdx.x * 4 + (threadIdx.x >> 6);
    int j = threadIdx.x & 63;
    if (i >= N_ITEM) return;
    float v = ldT<T>(feat, (size_t)i * 64 + j);
    float ss = wred(v * v);
    float inv = 1.f / fmaxf(sqrtf(ss), 1e-12f);
    x[(size_t)i * 64 + j] = v * inv;
}
__global__ void k_prep_items(const void* feat, float* x, const int* mode) {
    if (*mode) prep_items_body<float>(feat, x);
    else       prep_items_body<bf16>(feat, x);
}

// ---- user rows: normalize(tanh(uf @ W.T + b)) via transposed f32 weights ----
template<typename T>
__device__ __forceinline__ void prep_users_body(const void* uf, const float* wT,
                                                const void* b, float* x) {
    int u = blockIdx.x * 4 + (threadIdx.x >> 6);
    int j = threadIdx.x & 63;
    if (u >= N_USER) return;
    size_t ub = (size_t)u * 128;
    float acc = ldT<T>(b, j);
    #pragma unroll 8
    for (int k = 0; k < 128; k++)
        acc += ldT<T>(uf, ub + k) * wT[k * 64 + j];   // uf broadcast; wT coalesced
    float v = tanhf(acc);
    float ss = wred(v * v);
    float inv = 1.f / fmaxf(sqrtf(ss), 1e-12f);
    x[(size_t)(N_ITEM + u) * 64 + j] = v * inv;
}
__global__ void k_prep_users(const void* uf, const float* wT, const void* b,
                             float* x, const int* mode) {
    if (*mode) prep_users_body<float>(uf, wT, b, x);
    else       prep_users_body<bf16>(uf, wT, b, x);
}

// ---- xw = xin @ W (out_j = sum_k x_k * W[k*64+j]; W coalesced) ----
template<typename T>
__device__ __forceinline__ void xw_body(const float* xin, const void* W, float* xw) {
    int i = blockIdx.x * 4 + (threadIdx.x >> 6);
    int j = threadIdx.x & 63;
    if (i >= NN) return;
    float xv = xin[(size_t)i * 64 + j];
    float acc = 0.f;
    #pragma unroll
    for (int k = 0; k < 64; k++)
        acc += __shfl(xv, k, 64) * ldT<T>(W, (size_t)k * 64 + j);
    xw[(size_t)i * 64 + j] = acc;
}
__global__ void k_xw(const float* xin, const void* W, float* xw, const int* mode) {
    if (*mode) xw_body<float>(xin, W, xw);
    else       xw_body<bf16>(xin, W, xw);
}

// ---- edge pass 1: inner product, gate, logit; segment-max over dst ----
__global__ void k_edge1(const int* __restrict__ src, const int* __restrict__ dst,
                        const float* __restrict__ xw, const int* __restrict__ deg,
                        float* __restrict__ elog, unsigned* __restrict__ mkey) {
    int e = blockIdx.x * 4 + (threadIdx.x >> 6);
    if (e >= NE) return;
    int lane = threadIdx.x & 63;
    int s = src[e], d = dst[e];
    float a = xw[(size_t)s * 64 + lane];
    float c = xw[(size_t)d * 64 + lane];
    float inner = wred(a * c);
    if (lane == 0) {
        float dv = rsqrtf((float)deg[s]);
        float gate = 1.f / (1.f + expf(-dv * inner));
        float logit = inner * gate;
        elog[e] = logit;
        atomicMax(&mkey[d], fkey(logit));
    }
}

// ---- edge pass 2: e = exp(logit - m[dst]); segment-sum z ----
__global__ void k_edge2(const int* __restrict__ dst, const unsigned* __restrict__ mkey,
                        float* __restrict__ elog, float* __restrict__ z) {
    int e = blockIdx.x * blockDim.x + threadIdx.x;
    if (e >= NE) return;
    int d = dst[e];
    float m = funkey(mkey[d]);          // every d here received >=1 atomicMax
    float ev = expf(elog[e] - m);
    elog[e] = ev;                       // in-place: now holds exp value
    atomicAdd(&z[d], ev);
}

// ---- edge pass 3: scatter msg = xw[src] * attn into hacc[dst] ----
__global__ void k_edge3(const int* __restrict__ src, const int* __restrict__ dst,
                        const float* __restrict__ xw, const float* __restrict__ elog,
                        const float* __restrict__ z, float* __restrict__ hacc) {
    int e = blockIdx.x * 4 + (threadIdx.x >> 6);
    if (e >= NE) return;
    int lane = threadIdx.x & 63;
    int s = src[e], d = dst[e];
    float attn = elog[e] / (z[d] + 1e-16f);
    float xs = xw[(size_t)s * 64 + lane];
    atomicAdd(&hacc[(size_t)d * 64 + lane], xs * attn);
}

// ---- epilogue: x_next = leaky(leaky(h)@g.T + gb + leaky(x@lin.T + lb) + id)
//      gT/lT are pre-transposed f32 -> coalesced (fix for round-3 bottleneck)
template<typename T>
__device__ __forceinline__ void combine_body(const float* xin, const float* hacc,
                                             const float* gT, const void* gb,
                                             const float* lT, const void* lb,
                                             const void* id_emb,
                                             float* xnext, void* out, int off) {
    int i = blockIdx.x * 4 + (threadIdx.x >> 6);
    int j = threadIdx.x & 63;
    if (i >= NN) return;
    float hv = leaky(hacc[(size_t)i * 64 + j]);
    float xv = xin[(size_t)i * 64 + j];
    float accg = 0.f, accl = 0.f;
    #pragma unroll
    for (int k = 0; k < 64; k++) {
        float hk = __shfl(hv, k, 64);
        float xk = __shfl(xv, k, 64);
        accg += hk * gT[k * 64 + j];   // h @ g.T, coalesced
        accl += xk * lT[k * 64 + j];   // x @ lin.T, coalesced
    }
    float xhat = leaky(accl + ldT<T>(lb, j)) + ldT<T>(id_emb, (size_t)i * 64 + j);
    float xn = leaky(accg + ldT<T>(gb, j) + xhat);
    xnext[(size_t)i * 64 + j] = xn;
    stT<T>(out, (size_t)i * 128 + off + j, xn);
}
__global__ void k_combine(const float* xin, const float* hacc,
                          const float* gT, const void* gb,
                          const float* lT, const void* lb, const void* id_emb,
                          float* xnext, void* out, int off, const int* mode) {
    if (*mode) combine_body<float>(xin, hacc, gT, gb, lT, lb, id_emb, xnext, out, off);
    else       combine_body<bf16>(xin, hacc, gT, gb, lT, lb, id_emb, xnext, out, off);
}

static void run_layer(const int* src, const int* dst, const int* deg,
                      const float* xin, const void* gatw,
                      const float* lT, const void* lb,
                      const float* gT, const void* gb,
                      const void* id_emb,
                      float* xwbuf,      // also receives xnext (xw dead by then)
                      float* hacc, float* elog, unsigned* mkey, float* z,
                      void* out, int off, const int* mode, hipStream_t stream) {
    k_xw<<<(NN + 3) / 4, 256, 0, stream>>>(xin, gatw, xwbuf, mode);
    hipMemsetAsync(mkey, 0, NN * 4, stream);   // key 0 < every finite key
    hipMemsetAsync(z, 0, NN * 4, stream);
    hipMemsetAsync(hacc, 0, (size_t)NN * 64 * 4, stream);
    k_edge1<<<(NE + 3) / 4, 256, 0, stream>>>(src, dst, xwbuf, deg, elog, mkey);
    k_edge2<<<(NE + 255) / 256, 256, 0, stream>>>(dst, mkey, elog, z);
    k_edge3<<<(NE + 3) / 4, 256, 0, stream>>>(src, dst, xwbuf, elog, z, hacc);
    k_combine<<<(NN + 3) / 4, 256, 0, stream>>>(xin, hacc, gT, gb, lT, lb, id_emb,
                                                xwbuf, out, off, mode);
}

extern "C" void kernel_launch(void* const* d_in, const int* in_sizes, int n_in,
                              void* d_out, int out_size, void* d_ws, size_t ws_size,
                              hipStream_t stream) {
    const void* feat   = d_in[0];
    const void* uf     = d_in[1];
    const void* id_emb = d_in[2];
    const void* umw    = d_in[3];
    const void* umb    = d_in[4];
    const void* gat1   = d_in[5];
    const void* lin1w  = d_in[6];
    const void* lin1b  = d_in[7];
    const void* g1w    = d_in[8];
    const void* g1b    = d_in[9];
    const void* gat2   = d_in[10];
    const void* lin2w  = d_in[11];
    const void* lin2b  = d_in[12];
    const void* g2w    = d_in[13];
    const void* g2b    = d_in[14];
    const int*  ei     = (const int*)d_in[15];
    const int* src = ei;
    const int* dst = ei + NE;

    // workspace layout: small arrays first, then 3 rotating node buffers (~82 MB)
    int*      mode = (int*)d_ws;                       // 16 B slot
    int*      deg  = (int*)((char*)d_ws + 16);
    unsigned* mkey = (unsigned*)(deg + NN);
    float*    z    = (float*)(mkey + NN);
    float*    umwT = z + NN;                           // 8192 f32
    float*    wT   = umwT + 8192;                      // 4 x 4096 f32 (lT1,gT1,lT2,gT2)
    float*    elog = wT + 4 * 4096;
    float*    buf0 = elog + NE;                        // x
    float*    buf1 = buf0 + (size_t)NN * 64;           // xw1 / x1
    float*    buf2 = buf1 + (size_t)NN * 64;           // hacc

    k_detect<<<1, 256, 0, stream>>>((const unsigned short*)feat, mode);
    k_prep_w<<<96, 256, 0, stream>>>(umw, lin1w, g1w, lin2w, g2w, umwT, wT, mode);
    hipMemsetAsync(deg, 0, NN * 4, stream);
    k_deg<<<(NE + 255) / 256, 256, 0, stream>>>(src, deg);
    k_prep_items<<<(N_ITEM + 3) / 4, 256, 0, stream>>>(feat, buf0, mode);
    k_prep_users<<<(N_USER + 3) / 4, 256, 0, stream>>>(uf, umwT, umb, buf0, mode);

    const float* lT1 = wT;
    const float* gT1 = wT + 4096;
    const float* lT2 = wT + 8192;
    const float* gT2 = wT + 12288;

    // hop 1: buf0 -> buf1 (out cols 0..63)
    run_layer(src, dst, deg, buf0, gat1, lT1, lin1b, gT1, g1b, id_emb,
              buf1, buf2, elog, mkey, z, d_out, 0, mode, stream);
    // hop 2: buf1 -> buf0 (out cols 64..127)
    run_layer(src, dst, deg, buf1, gat2, lT2, lin2b, gT2, g2b, id_emb,
              buf0, buf2, elog, mkey, z, d_out, 64, mode, stream);
}

// Round 5
// 1150.509 us; speedup vs baseline: 1.9837x; 1.5196x over previous
//
#include <hip/hip_runtime.h>
#include <hip/hip_bf16.h>

// Problem constants (fixed by the reference's setup_inputs)
#define N_ITEM 80000
#define N_USER 20000
#define NN     100000   // N_ITEM + N_USER
#define NE     1000000  // edges
// dims: feat=64, user=128, id=64

typedef __hip_bfloat16 bf16;

__device__ __forceinline__ float b2f(bf16 v) { return __bfloat162float(v); }
__device__ __forceinline__ bf16  f2b(float v) { return __float2bfloat16(v); }
__device__ __forceinline__ float leaky(float v) { return v >= 0.f ? v : 0.01f * v; }

// dtype-adaptive load/store: T is the storage type of harness buffers
template<typename T>
__device__ __forceinline__ float ldT(const void* p, size_t i);
template<> __device__ __forceinline__ float ldT<float>(const void* p, size_t i) {
    return ((const float*)p)[i];
}
template<> __device__ __forceinline__ float ldT<bf16>(const void* p, size_t i) {
    return b2f(((const bf16*)p)[i]);
}
template<typename T>
__device__ __forceinline__ void stT(void* p, size_t i, float v);
template<> __device__ __forceinline__ void stT<float>(void* p, size_t i, float v) {
    ((float*)p)[i] = v;
}
template<> __device__ __forceinline__ void stT<bf16>(void* p, size_t i, float v) {
    ((bf16*)p)[i] = f2b(v);
}

// full 64-lane wave sum
__device__ __forceinline__ float wred(float v) {
    for (int o = 32; o; o >>= 1) v += __shfl_xor(v, o, 64);
    return v;
}

// ---- storage-dtype detection (bf16 vs f32 harness buffers) ----
__global__ void k_detect(const unsigned short* __restrict__ w, int* __restrict__ mode) {
    __shared__ int cnt[256];
    int bad = 0;
    for (int i = threadIdx.x; i < 4096; i += 256) {
        unsigned e = (w[i] >> 7) & 0xFFu;
        bad += (e == 0u || e == 0xFFu) ? 1 : 0;
    }
    cnt[threadIdx.x] = bad;
    __syncthreads();
    if (threadIdx.x == 0) {
        int t = 0;
        for (int k = 0; k < 256; k++) t += cnt[k];
        mode[0] = (t > 0) ? 1 : 0;   // 1 = float32 storage, 0 = bf16 storage
    }
}

// ---- transpose + f32-promote row-major weights (stride-gather fix, round 4) ----
__global__ void k_prep_w(const void* umw, const void* lw1, const void* gw1,
                         const void* lw2, const void* gw2,
                         float* umwT, float* wT, const int* mode) {
    int t = blockIdx.x * 256 + threadIdx.x;   // 0 .. 24575
    bool f32m = (*mode != 0);
    if (t < 8192) {
        int j = t >> 7, k = t & 127;
        float v = f32m ? ldT<float>(umw, t) : ldT<bf16>(umw, t);
        umwT[k * 64 + j] = v;
    } else {
        int u = t - 8192;
        int m = u >> 12;          // 0..3
        int r = u & 4095;
        int j = r >> 6, k = r & 63;
        const void* srcp = (m == 0) ? lw1 : (m == 1) ? gw1 : (m == 2) ? lw2 : gw2;
        float v = f32m ? ldT<float>(srcp, r) : ldT<bf16>(srcp, r);
        wT[m * 4096 + k * 64 + j] = v;
    }
}

// ---- degree counts: out-degree over src (gate) + in-degree over dst (CSR) ----
__global__ void k_deg(const int* __restrict__ src, const int* __restrict__ dst,
                      int* __restrict__ deg, int* __restrict__ cnt) {
    int e = blockIdx.x * blockDim.x + threadIdx.x;
    if (e < NE) {
        atomicAdd(&deg[src[e]], 1);
        atomicAdd(&cnt[dst[e]], 1);
    }
}

// ---- single-block exclusive scan: cnt[NN] -> csr_off[NN+1], cursor[NN] ----
__global__ void k_scan(const int* __restrict__ cnt, int* __restrict__ off,
                       int* __restrict__ cursor) {
    const int T = 1024, PER = (NN + T - 1) / T;   // 98
    __shared__ int sums[T];
    int base = threadIdx.x * PER;
    int s = 0;
    for (int r = 0; r < PER; r++) {
        int i = base + r;
        if (i < NN) s += cnt[i];
    }
    sums[threadIdx.x] = s;
    __syncthreads();
    // Hillis-Steele inclusive scan over 1024 partials
    for (int o = 1; o < T; o <<= 1) {
        int v = (threadIdx.x >= o) ? sums[threadIdx.x - o] : 0;
        __syncthreads();
        sums[threadIdx.x] += v;
        __syncthreads();
    }
    int run = (threadIdx.x == 0) ? 0 : sums[threadIdx.x - 1];
    for (int r = 0; r < PER; r++) {
        int i = base + r;
        if (i < NN) {
            off[i] = run;
            cursor[i] = run;
            run += cnt[i];
        }
    }
    if (threadIdx.x == T - 1) off[NN] = run;   // == NE
}

// ---- scatter edges into dst-sorted CSR (order within segment irrelevant) ----
__global__ void k_scatter(const int* __restrict__ src, const int* __restrict__ dst,
                          int* __restrict__ cursor, int* __restrict__ csr_src) {
    int e = blockIdx.x * blockDim.x + threadIdx.x;
    if (e < NE) {
        int pos = atomicAdd(&cursor[dst[e]], 1);
        csr_src[pos] = src[e];
    }
}

// ---- item rows: normalize(features) -> x[0:80000] ----
template<typename T>
__device__ __forceinline__ void prep_items_body(const void* feat, float* x) {
    int i = blockIdx.x * 4 + (threadIdx.x >> 6);
    int j = threadIdx.x & 63;
    if (i >= N_ITEM) return;
    float v = ldT<T>(feat, (size_t)i * 64 + j);
    float ss = wred(v * v);
    float inv = 1.f / fmaxf(sqrtf(ss), 1e-12f);
    x[(size_t)i * 64 + j] = v * inv;
}
__global__ void k_prep_items(const void* feat, float* x, const int* mode) {
    if (*mode) prep_items_body<float>(feat, x);
    else       prep_items_body<bf16>(feat, x);
}

// ---- user rows: normalize(tanh(uf @ W.T + b)) via transposed f32 weights ----
template<typename T>
__device__ __forceinline__ void prep_users_body(const void* uf, const float* wT,
                                                const void* b, float* x) {
    int u = blockIdx.x * 4 + (threadIdx.x >> 6);
    int j = threadIdx.x & 63;
    if (u >= N_USER) return;
    size_t ub = (size_t)u * 128;
    float acc = ldT<T>(b, j);
    #pragma unroll 8
    for (int k = 0; k < 128; k++)
        acc += ldT<T>(uf, ub + k) * wT[k * 64 + j];
    float v = tanhf(acc);
    float ss = wred(v * v);
    float inv = 1.f / fmaxf(sqrtf(ss), 1e-12f);
    x[(size_t)(N_ITEM + u) * 64 + j] = v * inv;
}
__global__ void k_prep_users(const void* uf, const float* wT, const void* b,
                             float* x, const int* mode) {
    if (*mode) prep_users_body<float>(uf, wT, b, x);
    else       prep_users_body<bf16>(uf, wT, b, x);
}

// ---- xw = xin @ W (out_j = sum_k x_k * W[k*64+j]; W coalesced) ----
template<typename T>
__device__ __forceinline__ void xw_body(const float* xin, const void* W, float* xw) {
    int i = blockIdx.x * 4 + (threadIdx.x >> 6);
    int j = threadIdx.x & 63;
    if (i >= NN) return;
    float xv = xin[(size_t)i * 64 + j];
    float acc = 0.f;
    #pragma unroll
    for (int k = 0; k < 64; k++)
        acc += __shfl(xv, k, 64) * ldT<T>(W, (size_t)k * 64 + j);
    xw[(size_t)i * 64 + j] = acc;
}
__global__ void k_xw(const float* xin, const void* W, float* xw, const int* mode) {
    if (*mode) xw_body<float>(xin, W, xw);
    else       xw_body<bf16>(xin, W, xw);
}

// ---- fused GAT layer: one wave per dst node.
// Online-softmax over the dst's CSR segment (== segment max/exp/sum exactly,
// l == z including the +1e-16), then the combine epilogue, all in registers.
template<typename T>
__device__ __forceinline__ void gat_body(const float* __restrict__ xw,
                                         const float* __restrict__ xin,
                                         const int* __restrict__ csr_off,
                                         const int* __restrict__ csr_src,
                                         const int* __restrict__ deg,
                                         const float* __restrict__ gT, const void* gb,
                                         const float* __restrict__ lT, const void* lb,
                                         const void* id_emb,
                                         float* __restrict__ xnext, void* out,
                                         int off_out) {
    int i = blockIdx.x * 4 + (threadIdx.x >> 6);
    int lane = threadIdx.x & 63;
    if (i >= NN) return;
    float xd = xw[(size_t)i * 64 + lane];
    int e0 = csr_off[i], e1 = csr_off[i + 1];
    float m = -1e30f, l = 0.f, acc = 0.f;
    for (int e = e0; e < e1; ++e) {
        int s = csr_src[e];                       // wave-uniform, L1 broadcast
        float xs = xw[(size_t)s * 64 + lane];     // 256 B gather
        float inner = wred(xd * xs);
        float dinv = rsqrtf((float)deg[s]);
        float gate = 1.f / (1.f + __expf(-dinv * inner));
        float logit = inner * gate;
        float mn = fmaxf(m, logit);
        float sc = __expf(m - mn);                // ==0 on first edge (m=-1e30)
        float w  = __expf(logit - mn);
        acc = acc * sc + w * xs;
        l   = l * sc + w;
        m = mn;
    }
    float h = acc / (l + 1e-16f);                 // deg-0 dst: 0/1e-16 = 0 (== ref)
    // combine epilogue
    float hv = leaky(h);
    float xv = xin[(size_t)i * 64 + lane];
    float accg = 0.f, accl = 0.f;
    #pragma unroll
    for (int k = 0; k < 64; k++) {
        accg += __shfl(hv, k, 64) * gT[k * 64 + lane];
        accl += __shfl(xv, k, 64) * lT[k * 64 + lane];
    }
    float xhat = leaky(accl + ldT<T>(lb, lane)) + ldT<T>(id_emb, (size_t)i * 64 + lane);
    float xn = leaky(accg + ldT<T>(gb, lane) + xhat);
    xnext[(size_t)i * 64 + lane] = xn;
    stT<T>(out, (size_t)i * 128 + off_out + lane, xn);
}
__global__ void k_gat(const float* xw, const float* xin,
                      const int* csr_off, const int* csr_src, const int* deg,
                      const float* gT, const void* gb,
                      const float* lT, const void* lb, const void* id_emb,
                      float* xnext, void* out, int off_out, const int* mode) {
    if (*mode) gat_body<float>(xw, xin, csr_off, csr_src, deg, gT, gb, lT, lb,
                               id_emb, xnext, out, off_out);
    else       gat_body<bf16>(xw, xin, csr_off, csr_src, deg, gT, gb, lT, lb,
                              id_emb, xnext, out, off_out);
}

extern "C" void kernel_launch(void* const* d_in, const int* in_sizes, int n_in,
                              void* d_out, int out_size, void* d_ws, size_t ws_size,
                              hipStream_t stream) {
    const void* feat   = d_in[0];
    const void* uf     = d_in[1];
    const void* id_emb = d_in[2];
    const void* umw    = d_in[3];
    const void* umb    = d_in[4];
    const void* gat1   = d_in[5];
    const void* lin1b  = d_in[7];
    const void* g1b    = d_in[9];
    const void* gat2   = d_in[10];
    const void* lin2b  = d_in[12];
    const void* g2b    = d_in[14];
    const int*  ei     = (const int*)d_in[15];
    const int* src = ei;
    const int* dst = ei + NE;

    // workspace layout (~82.5 MB)
    int*      mode   = (int*)d_ws;                       // 16 B slot
    int*      deg    = (int*)((char*)d_ws + 16);         // NN
    int*      cnt    = deg + NN;                         // NN (in-degree counts)
    int*      cursor = cnt + NN;                         // NN
    int*      csr_off = cursor + NN;                     // NN+16
    float*    umwT   = (float*)(csr_off + NN + 16);      // 8192
    float*    wT     = umwT + 8192;                      // 4 x 4096
    int*      csr_src = (int*)(wT + 4 * 4096);           // NE
    float*    buf0   = (float*)(csr_src + NE);           // x     (25.6 MB)
    float*    buf1   = buf0 + (size_t)NN * 64;           // xw    (25.6 MB)
    float*    buf2   = buf1 + (size_t)NN * 64;           // x1/x2 (25.6 MB)

    k_detect<<<1, 256, 0, stream>>>((const unsigned short*)feat, mode);
    k_prep_w<<<96, 256, 0, stream>>>(umw, d_in[6], d_in[8], d_in[11], d_in[13],
                                     umwT, wT, mode);
    hipMemsetAsync(deg, 0, NN * 4, stream);
    hipMemsetAsync(cnt, 0, NN * 4, stream);
    k_deg<<<(NE + 255) / 256, 256, 0, stream>>>(src, dst, deg, cnt);
    k_scan<<<1, 1024, 0, stream>>>(cnt, csr_off, cursor);
    k_scatter<<<(NE + 255) / 256, 256, 0, stream>>>(src, dst, cursor, csr_src);
    k_prep_items<<<(N_ITEM + 3) / 4, 256, 0, stream>>>(feat, buf0, mode);
    k_prep_users<<<(N_USER + 3) / 4, 256, 0, stream>>>(uf, umwT, umb, buf0, mode);

    const float* lT1 = wT;
    const float* gT1 = wT + 4096;
    const float* lT2 = wT + 8192;
    const float* gT2 = wT + 12288;

    // hop 1: x(buf0) -> xw1(buf1) -> x1(buf2), out cols 0..63
    k_xw<<<(NN + 3) / 4, 256, 0, stream>>>(buf0, gat1, buf1, mode);
    k_gat<<<(NN + 3) / 4, 256, 0, stream>>>(buf1, buf0, csr_off, csr_src, deg,
                                            gT1, g1b, lT1, lin1b, id_emb,
                                            buf2, d_out, 0, mode);
    // hop 2: x1(buf2) -> xw2(buf1) -> x2(buf0), out cols 64..127
    k_xw<<<(NN + 3) / 4, 256, 0, stream>>>(buf2, gat2, buf1, mode);
    k_gat<<<(NN + 3) / 4, 256, 0, stream>>>(buf1, buf2, csr_off, csr_src, deg,
                                            gT2, g2b, lT2, lin2b, id_emb,
                                            buf0, d_out, 64, mode);
}

// Round 6
// 883.113 us; speedup vs baseline: 2.5843x; 1.3028x over previous
//
#include <hip/hip_runtime.h>
#include <hip/hip_bf16.h>

// Problem constants (fixed by the reference's setup_inputs)
#define N_ITEM 80000
#define N_USER 20000
#define NN     100000   // N_ITEM + N_USER
#define NE     1000000  // edges
#define SCAN_T 1024
#define SCAN_TILES ((NN + SCAN_T - 1) / SCAN_T)   // 98

typedef __hip_bfloat16 bf16;

__device__ __forceinline__ float b2f(bf16 v) { return __bfloat162float(v); }
__device__ __forceinline__ bf16  f2b(float v) { return __float2bfloat16(v); }
__device__ __forceinline__ float leaky(float v) { return v >= 0.f ? v : 0.01f * v; }

// dtype-adaptive load/store: T is the storage type of harness buffers
template<typename T>
__device__ __forceinline__ float ldT(const void* p, size_t i);
template<> __device__ __forceinline__ float ldT<float>(const void* p, size_t i) {
    return ((const float*)p)[i];
}
template<> __device__ __forceinline__ float ldT<bf16>(const void* p, size_t i) {
    return b2f(((const bf16*)p)[i]);
}
template<typename T>
__device__ __forceinline__ void stT(void* p, size_t i, float v);
template<> __device__ __forceinline__ void stT<float>(void* p, size_t i, float v) {
    ((float*)p)[i] = v;
}
template<> __device__ __forceinline__ void stT<bf16>(void* p, size_t i, float v) {
    ((bf16*)p)[i] = f2b(v);
}

// full 64-lane wave sum (float)
__device__ __forceinline__ float wred(float v) {
    for (int o = 32; o; o >>= 1) v += __shfl_xor(v, o, 64);
    return v;
}
// 64-lane inclusive scan (int)
__device__ __forceinline__ int wscan(int v, int lane) {
    for (int o = 1; o < 64; o <<= 1) {
        int t = __shfl_up(v, o, 64);
        v += (lane >= o) ? t : 0;
    }
    return v;
}

// ---- storage-dtype detection (bf16 vs f32 harness buffers) ----
__global__ void k_detect(const unsigned short* __restrict__ w, int* __restrict__ mode) {
    __shared__ int cnt[256];
    int bad = 0;
    for (int i = threadIdx.x; i < 4096; i += 256) {
        unsigned e = (w[i] >> 7) & 0xFFu;
        bad += (e == 0u || e == 0xFFu) ? 1 : 0;
    }
    cnt[threadIdx.x] = bad;
    __syncthreads();
    if (threadIdx.x == 0) {
        int t = 0;
        for (int k = 0; k < 256; k++) t += cnt[k];
        mode[0] = (t > 0) ? 1 : 0;   // 1 = float32 storage, 0 = bf16 storage
    }
}

// ---- transpose + f32-promote row-major weights (stride-gather fix, round 4) ----
__global__ void k_prep_w(const void* umw, const void* lw1, const void* gw1,
                         const void* lw2, const void* gw2,
                         float* umwT, float* wT, const int* mode) {
    int t = blockIdx.x * 256 + threadIdx.x;   // 0 .. 24575
    bool f32m = (*mode != 0);
    if (t < 8192) {
        int j = t >> 7, k = t & 127;
        float v = f32m ? ldT<float>(umw, t) : ldT<bf16>(umw, t);
        umwT[k * 64 + j] = v;
    } else {
        int u = t - 8192;
        int m = u >> 12;          // 0..3
        int r = u & 4095;
        int j = r >> 6, k = r & 63;
        const void* srcp = (m == 0) ? lw1 : (m == 1) ? gw1 : (m == 2) ? lw2 : gw2;
        float v = f32m ? ldT<float>(srcp, r) : ldT<bf16>(srcp, r);
        wT[m * 4096 + k * 64 + j] = v;
    }
}

// ---- degree counts: out-degree over src (gate) + in-degree over dst (CSR) ----
__global__ void k_deg(const int* __restrict__ src, const int* __restrict__ dst,
                      int* __restrict__ deg, int* __restrict__ cnt) {
    int e = blockIdx.x * blockDim.x + threadIdx.x;
    if (e < NE) {
        atomicAdd(&deg[src[e]], 1);
        atomicAdd(&cnt[dst[e]], 1);
    }
}

// ---- parallel scan, pass 1: per-tile sums (98 blocks x 1024 thr) ----
__global__ void k_scan_sum(const int* __restrict__ cnt, int* __restrict__ tsum) {
    __shared__ int wsum[16];
    int i = blockIdx.x * SCAN_T + threadIdx.x;
    int lane = threadIdx.x & 63, wid = threadIdx.x >> 6;
    int v = (i < NN) ? cnt[i] : 0;
    float s = wred((float)v);               // exact: counts < 2^24
    if (lane == 0) wsum[wid] = (int)s;
    __syncthreads();
    if (threadIdx.x == 0) {
        int t = 0;
        #pragma unroll
        for (int k = 0; k < 16; k++) t += wsum[k];
        tsum[blockIdx.x] = t;
    }
}

// ---- pass 2: exclusive scan of the 98 tile sums (1 block) ----
__global__ void k_scan_tiles(const int* __restrict__ tsum, int* __restrict__ toff) {
    __shared__ int wsum[16];
    int lane = threadIdx.x & 63, wid = threadIdx.x >> 6;
    int v = (threadIdx.x < SCAN_TILES) ? tsum[threadIdx.x] : 0;
    int inc = wscan(v, lane);
    if (lane == 63) wsum[wid] = inc;
    __syncthreads();
    if (wid == 0) {
        int ws = (lane < 16) ? wsum[lane] : 0;
        int wi = wscan(ws, lane);
        if (lane < 16) wsum[lane] = wi - ws;   // exclusive wave offsets
    }
    __syncthreads();
    if (threadIdx.x < SCAN_TILES) toff[threadIdx.x] = inc - v + wsum[wid];
}

// ---- pass 3: block-local exclusive scan + tile offset -> csr_off, cursor ----
__global__ void k_scan_out(const int* __restrict__ cnt, const int* __restrict__ toff,
                           int* __restrict__ csr_off, int* __restrict__ cursor) {
    __shared__ int wsum[16];
    int i = blockIdx.x * SCAN_T + threadIdx.x;
    int lane = threadIdx.x & 63, wid = threadIdx.x >> 6;
    int v = (i < NN) ? cnt[i] : 0;
    int inc = wscan(v, lane);
    if (lane == 63) wsum[wid] = inc;
    __syncthreads();
    if (wid == 0) {
        int ws = (lane < 16) ? wsum[lane] : 0;
        int wi = wscan(ws, lane);
        if (lane < 16) wsum[lane] = wi - ws;
    }
    __syncthreads();
    int excl = inc - v + wsum[wid] + toff[blockIdx.x];
    if (i < NN) { csr_off[i] = excl; cursor[i] = excl; }
    if (i == NN - 1) csr_off[NN] = excl + v;   // == NE
}

// ---- scatter edges into dst-sorted CSR (order within segment irrelevant) ----
__global__ void k_scatter(const int* __restrict__ src, const int* __restrict__ dst,
                          int* __restrict__ cursor, int* __restrict__ csr_src) {
    int e = blockIdx.x * blockDim.x + threadIdx.x;
    if (e < NE) {
        int pos = atomicAdd(&cursor[dst[e]], 1);
        csr_src[pos] = src[e];
    }
}

// ---- item rows: normalize(features) -> x[0:80000] ----
template<typename T>
__device__ __forceinline__ void prep_items_body(const void* feat, float* x) {
    int i = blockIdx.x * 4 + (threadIdx.x >> 6);
    int j = threadIdx.x & 63;
    if (i >= N_ITEM) return;
    float v = ldT<T>(feat, (size_t)i * 64 + j);
    float ss = wred(v * v);
    float inv = 1.f / fmaxf(sqrtf(ss), 1e-12f);
    x[(size_t)i * 64 + j] = v * inv;
}
__global__ void k_prep_items(const void* feat, float* x, const int* mode) {
    if (*mode) prep_items_body<float>(feat, x);
    else       prep_items_body<bf16>(feat, x);
}

// ---- user rows: normalize(tanh(uf @ W.T + b)) via transposed f32 weights ----
template<typename T>
__device__ __forceinline__ void prep_users_body(const void* uf, const float* wT,
                                                const void* b, float* x) {
    int u = blockIdx.x * 4 + (threadIdx.x >> 6);
    int j = threadIdx.x & 63;
    if (u >= N_USER) return;
    size_t ub = (size_t)u * 128;
    float acc = ldT<T>(b, j);
    #pragma unroll 8
    for (int k = 0; k < 128; k++)
        acc += ldT<T>(uf, ub + k) * wT[k * 64 + j];
    float v = tanhf(acc);
    float ss = wred(v * v);
    float inv = 1.f / fmaxf(sqrtf(ss), 1e-12f);
    x[(size_t)(N_ITEM + u) * 64 + j] = v * inv;
}
__global__ void k_prep_users(const void* uf, const float* wT, const void* b,
                             float* x, const int* mode) {
    if (*mode) prep_users_body<float>(uf, wT, b, x);
    else       prep_users_body<bf16>(uf, wT, b, x);
}

// ---- xw = xin @ W (out_j = sum_k x_k * W[k*64+j]; W coalesced) ----
template<typename T>
__device__ __forceinline__ void xw_body(const float* xin, const void* W, float* xw) {
    int i = blockIdx.x * 4 + (threadIdx.x >> 6);
    int j = threadIdx.x & 63;
    if (i >= NN) return;
    float xv = xin[(size_t)i * 64 + j];
    float acc = 0.f;
    #pragma unroll
    for (int k = 0; k < 64; k++)
        acc += __shfl(xv, k, 64) * ldT<T>(W, (size_t)k * 64 + j);
    xw[(size_t)i * 64 + j] = acc;
}
__global__ void k_xw(const float* xin, const void* W, float* xw, const int* mode) {
    if (*mode) xw_body<float>(xin, W, xw);
    else       xw_body<bf16>(xin, W, xw);
}

// ---- fused GAT layer: one wave per dst node, online softmax + epilogue.
// Edge loop software-pipelined: next edge's src/gather/deg prefetched one
// iteration ahead to break the gather->wred->exp dependency chain.
template<typename T>
__device__ __forceinline__ void gat_body(const float* __restrict__ xw,
                                         const float* __restrict__ xin,
                                         const int* __restrict__ csr_off,
                                         const int* __restrict__ csr_src,
                                         const int* __restrict__ deg,
                                         const float* __restrict__ gT, const void* gb,
                                         const float* __restrict__ lT, const void* lb,
                                         const void* id_emb,
                                         float* __restrict__ xnext, void* out,
                                         int off_out) {
    int i = blockIdx.x * 4 + (threadIdx.x >> 6);
    int lane = threadIdx.x & 63;
    if (i >= NN) return;
    float xd = xw[(size_t)i * 64 + lane];
    int e0 = csr_off[i], e1 = csr_off[i + 1];
    float m = -1e30f, l = 0.f, acc = 0.f;
    float xsP = 0.f, dP = 1.f;
    if (e0 < e1) {
        int s0 = csr_src[e0];
        xsP = xw[(size_t)s0 * 64 + lane];
        dP = (float)deg[s0];
    }
    for (int e = e0; e < e1; ++e) {
        float xs = xsP, dv = dP;
        if (e + 1 < e1) {                          // wave-uniform branch
            int sn = csr_src[e + 1];
            xsP = xw[(size_t)sn * 64 + lane];
            dP = (float)deg[sn];
        }
        float inner = wred(xd * xs);
        float gate = 1.f / (1.f + __expf(-rsqrtf(dv) * inner));
        float logit = inner * gate;
        float mn = fmaxf(m, logit);
        float sc = __expf(m - mn);                 // ==0 on first edge (m=-1e30)
        float w  = __expf(logit - mn);
        acc = acc * sc + w * xs;
        l   = l * sc + w;
        m = mn;
    }
    float h = acc / (l + 1e-16f);                  // deg-0 dst: 0 (== ref)
    // combine epilogue
    float hv = leaky(h);
    float xv = xin[(size_t)i * 64 + lane];
    float accg = 0.f, accl = 0.f;
    #pragma unroll
    for (int k = 0; k < 64; k++) {
        accg += __shfl(hv, k, 64) * gT[k * 64 + lane];
        accl += __shfl(xv, k, 64) * lT[k * 64 + lane];
    }
    float xhat = leaky(accl + ldT<T>(lb, lane)) + ldT<T>(id_emb, (size_t)i * 64 + lane);
    float xn = leaky(accg + ldT<T>(gb, lane) + xhat);
    xnext[(size_t)i * 64 + lane] = xn;
    stT<T>(out, (size_t)i * 128 + off_out + lane, xn);
}
__global__ void k_gat(const float* xw, const float* xin,
                      const int* csr_off, const int* csr_src, const int* deg,
                      const float* gT, const void* gb,
                      const float* lT, const void* lb, const void* id_emb,
                      float* xnext, void* out, int off_out, const int* mode) {
    if (*mode) gat_body<float>(xw, xin, csr_off, csr_src, deg, gT, gb, lT, lb,
                               id_emb, xnext, out, off_out);
    else       gat_body<bf16>(xw, xin, csr_off, csr_src, deg, gT, gb, lT, lb,
                              id_emb, xnext, out, off_out);
}

extern "C" void kernel_launch(void* const* d_in, const int* in_sizes, int n_in,
                              void* d_out, int out_size, void* d_ws, size_t ws_size,
                              hipStream_t stream) {
    const void* feat   = d_in[0];
    const void* uf     = d_in[1];
    const void* id_emb = d_in[2];
    const void* umw    = d_in[3];
    const void* umb    = d_in[4];
    const void* gat1   = d_in[5];
    const void* lin1b  = d_in[7];
    const void* g1b    = d_in[9];
    const void* gat2   = d_in[10];
    const void* lin2b  = d_in[12];
    const void* g2b    = d_in[14];
    const int*  ei     = (const int*)d_in[15];
    const int* src = ei;
    const int* dst = ei + NE;

    // workspace layout (~82.6 MB)
    int*      mode   = (int*)d_ws;                       // 16 B slot
    int*      deg    = (int*)((char*)d_ws + 16);         // NN
    int*      cnt    = deg + NN;                         // NN (in-degree counts)
    int*      cursor = cnt + NN;                         // NN
    int*      csr_off = cursor + NN;                     // NN+16
    int*      tsum   = csr_off + NN + 16;                // 128
    int*      toff   = tsum + 128;                       // 128
    float*    umwT   = (float*)(toff + 128);             // 8192
    float*    wT     = umwT + 8192;                      // 4 x 4096
    int*      csr_src = (int*)(wT + 4 * 4096);           // NE
    float*    buf0   = (float*)(csr_src + NE);           // x     (25.6 MB)
    float*    buf1   = buf0 + (size_t)NN * 64;           // xw    (25.6 MB)
    float*    buf2   = buf1 + (size_t)NN * 64;           // x1/x2 (25.6 MB)

    k_detect<<<1, 256, 0, stream>>>((const unsigned short*)feat, mode);
    k_prep_w<<<96, 256, 0, stream>>>(umw, d_in[6], d_in[8], d_in[11], d_in[13],
                                     umwT, wT, mode);
    hipMemsetAsync(deg, 0, NN * 4, stream);
    hipMemsetAsync(cnt, 0, NN * 4, stream);
    k_deg<<<(NE + 255) / 256, 256, 0, stream>>>(src, dst, deg, cnt);
    k_scan_sum<<<SCAN_TILES, SCAN_T, 0, stream>>>(cnt, tsum);
    k_scan_tiles<<<1, SCAN_T, 0, stream>>>(tsum, toff);
    k_scan_out<<<SCAN_TILES, SCAN_T, 0, stream>>>(cnt, toff, csr_off, cursor);
    k_scatter<<<(NE + 255) / 256, 256, 0, stream>>>(src, dst, cursor, csr_src);
    k_prep_items<<<(N_ITEM + 3) / 4, 256, 0, stream>>>(feat, buf0, mode);
    k_prep_users<<<(N_USER + 3) / 4, 256, 0, stream>>>(uf, umwT, umb, buf0, mode);

    const float* lT1 = wT;
    const float* gT1 = wT + 4096;
    const float* lT2 = wT + 8192;
    const float* gT2 = wT + 12288;

    // hop 1: x(buf0) -> xw1(buf1) -> x1(buf2), out cols 0..63
    k_xw<<<(NN + 3) / 4, 256, 0, stream>>>(buf0, gat1, buf1, mode);
    k_gat<<<(NN + 3) / 4, 256, 0, stream>>>(buf1, buf0, csr_off, csr_src, deg,
                                            gT1, g1b, lT1, lin1b, id_emb,
                                            buf2, d_out, 0, mode);
    // hop 2: x1(buf2) -> xw2(buf1) -> x2(buf0), out cols 64..127
    k_xw<<<(NN + 3) / 4, 256, 0, stream>>>(buf2, gat2, buf1, mode);
    k_gat<<<(NN + 3) / 4, 256, 0, stream>>>(buf1, buf2, csr_off, csr_src, deg,
                                            gT2, g2b, lT2, lin2b, id_emb,
                                            buf0, d_out, 64, mode);
}

// Round 7
// 698.159 us; speedup vs baseline: 3.2689x; 1.2649x over previous
//
#include <hip/hip_runtime.h>
#include <hip/hip_bf16.h>

// Problem constants (fixed by the reference's setup_inputs)
#define N_ITEM 80000
#define N_USER 20000
#define NN     100000   // N_ITEM + N_USER
#define NE     1000000  // edges
#define SCAN_T 1024
#define SCAN_TILES ((NN + SCAN_T - 1) / SCAN_T)   // 98

typedef __hip_bfloat16 bf16;

__device__ __forceinline__ float b2f(bf16 v) { return __bfloat162float(v); }
__device__ __forceinline__ bf16  f2b(float v) { return __float2bfloat16(v); }
__device__ __forceinline__ float bits2f(unsigned short h) {
    return __uint_as_float(((unsigned)h) << 16);
}
__device__ __forceinline__ float leaky(float v) { return v >= 0.f ? v : 0.01f * v; }

// dtype-adaptive scalar load/store
template<typename T>
__device__ __forceinline__ float ldT(const void* p, size_t i);
template<> __device__ __forceinline__ float ldT<float>(const void* p, size_t i) {
    return ((const float*)p)[i];
}
template<> __device__ __forceinline__ float ldT<bf16>(const void* p, size_t i) {
    return b2f(((const bf16*)p)[i]);
}
// dtype-adaptive float4 load/store (i must be a multiple of 4)
template<typename T>
__device__ __forceinline__ float4 ldT4(const void* p, size_t i);
template<> __device__ __forceinline__ float4 ldT4<float>(const void* p, size_t i) {
    return *(const float4*)((const float*)p + i);
}
template<> __device__ __forceinline__ float4 ldT4<bf16>(const void* p, size_t i) {
    ushort4 u = *(const ushort4*)((const unsigned short*)p + i);
    return make_float4(bits2f(u.x), bits2f(u.y), bits2f(u.z), bits2f(u.w));
}
template<typename T>
__device__ __forceinline__ void stT4(void* p, size_t i, float4 v);
template<> __device__ __forceinline__ void stT4<float>(void* p, size_t i, float4 v) {
    *(float4*)((float*)p + i) = v;
}
template<> __device__ __forceinline__ void stT4<bf16>(void* p, size_t i, float4 v) {
    bf16 b0 = f2b(v.x), b1 = f2b(v.y), b2 = f2b(v.z), b3 = f2b(v.w);
    ushort4 u = make_ushort4(*(unsigned short*)&b0, *(unsigned short*)&b1,
                             *(unsigned short*)&b2, *(unsigned short*)&b3);
    *(ushort4*)((unsigned short*)p + i) = u;
}
__device__ __forceinline__ float4 ld4f(const float* p, size_t i) {
    return *(const float4*)(p + i);
}

// full 64-lane wave sum (float)
__device__ __forceinline__ float wred(float v) {
    for (int o = 32; o; o >>= 1) v += __shfl_xor(v, o, 64);
    return v;
}
// 16-lane group sum (stays within the lane's 16-lane group)
__device__ __forceinline__ float gred16(float v) {
    for (int o = 8; o; o >>= 1) v += __shfl_xor(v, o, 64);
    return v;
}
// 64-lane inclusive scan (int)
__device__ __forceinline__ int wscan(int v, int lane) {
    for (int o = 1; o < 64; o <<= 1) {
        int t = __shfl_up(v, o, 64);
        v += (lane >= o) ? t : 0;
    }
    return v;
}

// ---- storage-dtype detection (bf16 vs f32 harness buffers) ----
__global__ void k_detect(const unsigned short* __restrict__ w, int* __restrict__ mode) {
    __shared__ int cnt[256];
    int bad = 0;
    for (int i = threadIdx.x; i < 4096; i += 256) {
        unsigned e = (w[i] >> 7) & 0xFFu;
        bad += (e == 0u || e == 0xFFu) ? 1 : 0;
    }
    cnt[threadIdx.x] = bad;
    __syncthreads();
    if (threadIdx.x == 0) {
        int t = 0;
        for (int k = 0; k < 256; k++) t += cnt[k];
        mode[0] = (t > 0) ? 1 : 0;   // 1 = float32 storage, 0 = bf16 storage
    }
}

// ---- transpose + f32-promote row-major weights (stride-gather fix, round 4) ----
__global__ void k_prep_w(const void* umw, const void* lw1, const void* gw1,
                         const void* lw2, const void* gw2,
                         float* umwT, float* wT, const int* mode) {
    int t = blockIdx.x * 256 + threadIdx.x;   // 0 .. 24575
    bool f32m = (*mode != 0);
    if (t < 8192) {
        int j = t >> 7, k = t & 127;
        float v = f32m ? ldT<float>(umw, t) : ldT<bf16>(umw, t);
        umwT[k * 64 + j] = v;
    } else {
        int u = t - 8192;
        int m = u >> 12;          // 0..3
        int r = u & 4095;
        int j = r >> 6, k = r & 63;
        const void* srcp = (m == 0) ? lw1 : (m == 1) ? gw1 : (m == 2) ? lw2 : gw2;
        float v = f32m ? ldT<float>(srcp, r) : ldT<bf16>(srcp, r);
        wT[m * 4096 + k * 64 + j] = v;
    }
}

// ---- degree counts: out-degree over src (gate) + in-degree over dst (CSR) ----
__global__ void k_deg(const int* __restrict__ src, const int* __restrict__ dst,
                      int* __restrict__ deg, int* __restrict__ cnt) {
    int e = blockIdx.x * blockDim.x + threadIdx.x;
    if (e < NE) {
        atomicAdd(&deg[src[e]], 1);
        atomicAdd(&cnt[dst[e]], 1);
    }
}

// ---- parallel scan, pass 1: per-tile sums ----
__global__ void k_scan_sum(const int* __restrict__ cnt, int* __restrict__ tsum) {
    __shared__ int wsum[16];
    int i = blockIdx.x * SCAN_T + threadIdx.x;
    int lane = threadIdx.x & 63, wid = threadIdx.x >> 6;
    int v = (i < NN) ? cnt[i] : 0;
    float s = wred((float)v);               // exact: counts < 2^24
    if (lane == 0) wsum[wid] = (int)s;
    __syncthreads();
    if (threadIdx.x == 0) {
        int t = 0;
        #pragma unroll
        for (int k = 0; k < 16; k++) t += wsum[k];
        tsum[blockIdx.x] = t;
    }
}

// ---- pass 2: exclusive scan of the tile sums (1 block) ----
__global__ void k_scan_tiles(const int* __restrict__ tsum, int* __restrict__ toff) {
    __shared__ int wsum[16];
    int lane = threadIdx.x & 63, wid = threadIdx.x >> 6;
    int v = (threadIdx.x < SCAN_TILES) ? tsum[threadIdx.x] : 0;
    int inc = wscan(v, lane);
    if (lane == 63) wsum[wid] = inc;
    __syncthreads();
    if (wid == 0) {
        int ws = (lane < 16) ? wsum[lane] : 0;
        int wi = wscan(ws, lane);
        if (lane < 16) wsum[lane] = wi - ws;   // exclusive wave offsets
    }
    __syncthreads();
    if (threadIdx.x < SCAN_TILES) toff[threadIdx.x] = inc - v + wsum[wid];
}

// ---- pass 3: block-local exclusive scan + tile offset -> csr_off, cursor ----
__global__ void k_scan_out(const int* __restrict__ cnt, const int* __restrict__ toff,
                           int* __restrict__ csr_off, int* __restrict__ cursor) {
    __shared__ int wsum[16];
    int i = blockIdx.x * SCAN_T + threadIdx.x;
    int lane = threadIdx.x & 63, wid = threadIdx.x >> 6;
    int v = (i < NN) ? cnt[i] : 0;
    int inc = wscan(v, lane);
    if (lane == 63) wsum[wid] = inc;
    __syncthreads();
    if (wid == 0) {
        int ws = (lane < 16) ? wsum[lane] : 0;
        int wi = wscan(ws, lane);
        if (lane < 16) wsum[lane] = wi - ws;
    }
    __syncthreads();
    int excl = inc - v + wsum[wid] + toff[blockIdx.x];
    if (i < NN) { csr_off[i] = excl; cursor[i] = excl; }
    if (i == NN - 1) csr_off[NN] = excl + v;   // == NE
}

// ---- scatter edges into dst-sorted CSR ----
__global__ void k_scatter(const int* __restrict__ src, const int* __restrict__ dst,
                          int* __restrict__ cursor, int* __restrict__ csr_src) {
    int e = blockIdx.x * blockDim.x + threadIdx.x;
    if (e < NE) {
        int pos = atomicAdd(&cursor[dst[e]], 1);
        csr_src[pos] = src[e];
    }
}

// ---- item rows: normalize(features) -> x[0:80000] ----
template<typename T>
__device__ __forceinline__ void prep_items_body(const void* feat, float* x) {
    int i = blockIdx.x * 4 + (threadIdx.x >> 6);
    int j = threadIdx.x & 63;
    if (i >= N_ITEM) return;
    float v = ldT<T>(feat, (size_t)i * 64 + j);
    float ss = wred(v * v);
    float inv = 1.f / fmaxf(sqrtf(ss), 1e-12f);
    x[(size_t)i * 64 + j] = v * inv;
}
__global__ void k_prep_items(const void* feat, float* x, const int* mode) {
    if (*mode) prep_items_body<float>(feat, x);
    else       prep_items_body<bf16>(feat, x);
}

// ---- user rows: normalize(tanh(uf @ W.T + b)) via transposed f32 weights ----
template<typename T>
__device__ __forceinline__ void prep_users_body(const void* uf, const float* wT,
                                                const void* b, float* x) {
    int u = blockIdx.x * 4 + (threadIdx.x >> 6);
    int j = threadIdx.x & 63;
    if (u >= N_USER) return;
    size_t ub = (size_t)u * 128;
    float acc = ldT<T>(b, j);
    #pragma unroll 8
    for (int k = 0; k < 128; k++)
        acc += ldT<T>(uf, ub + k) * wT[k * 64 + j];
    float v = tanhf(acc);
    float ss = wred(v * v);
    float inv = 1.f / fmaxf(sqrtf(ss), 1e-12f);
    x[(size_t)(N_ITEM + u) * 64 + j] = v * inv;
}
__global__ void k_prep_users(const void* uf, const float* wT, const void* b,
                             float* x, const int* mode) {
    if (*mode) prep_users_body<float>(uf, wT, b, x);
    else       prep_users_body<bf16>(uf, wT, b, x);
}

// ---- xw = xin @ W, 16 lanes/node x float4 (4 nodes/wave, 16 nodes/block) ----
template<typename T>
__device__ __forceinline__ void xw_body(const float* __restrict__ xin,
                                        const void* __restrict__ W,
                                        float* __restrict__ xw) {
    int lane = threadIdx.x & 63, wid = threadIdx.x >> 6;
    int sl = lane & 15;
    int i = blockIdx.x * 16 + (wid << 2) + (lane >> 4);
    if (i >= NN) return;
    size_t rb = (size_t)i * 64 + sl * 4;
    float4 xv = ld4f(xin, rb);
    float4 acc = make_float4(0.f, 0.f, 0.f, 0.f);
    int gbase = lane & 48;
    #pragma unroll
    for (int kk = 0; kk < 16; kk++) {
        int srcl = gbase | kk;
        float xb[4];
        xb[0] = __shfl(xv.x, srcl, 64);
        xb[1] = __shfl(xv.y, srcl, 64);
        xb[2] = __shfl(xv.z, srcl, 64);
        xb[3] = __shfl(xv.w, srcl, 64);
        #pragma unroll
        for (int q = 0; q < 4; q++) {
            float4 w4 = ldT4<T>(W, (size_t)(kk * 4 + q) * 64 + sl * 4);
            acc.x += xb[q] * w4.x; acc.y += xb[q] * w4.y;
            acc.z += xb[q] * w4.z; acc.w += xb[q] * w4.w;
        }
    }
    *(float4*)(xw + rb) = acc;
}
__global__ void k_xw(const float* xin, const void* W, float* xw, const int* mode) {
    if (*mode) xw_body<float>(xin, W, xw);
    else       xw_body<bf16>(xin, W, xw);
}

// ---- fused GAT layer: 16 lanes/node x float4, 4 nodes/wave.
// Online softmax over the dst's CSR segment + combine epilogue, in registers.
template<typename T>
__device__ __forceinline__ void gat_body(const float* __restrict__ xw,
                                         const float* __restrict__ xin,
                                         const int* __restrict__ csr_off,
                                         const int* __restrict__ csr_src,
                                         const int* __restrict__ deg,
                                         const float* __restrict__ gT, const void* gb,
                                         const float* __restrict__ lT, const void* lb,
                                         const void* id_emb,
                                         float* __restrict__ xnext, void* out,
                                         int off_out) {
    int lane = threadIdx.x & 63, wid = threadIdx.x >> 6;
    int sl = lane & 15;
    int i = blockIdx.x * 16 + (wid << 2) + (lane >> 4);
    if (i >= NN) return;
    size_t rb = (size_t)i * 64 + sl * 4;
    float4 xd = ld4f(xw, rb);
    int e0 = csr_off[i], e1 = csr_off[i + 1];
    int cnt = e1 - e0;
    float m = -1e30f, l = 0.f;
    float4 acc = make_float4(0.f, 0.f, 0.f, 0.f);
    float4 xsP = make_float4(0.f, 0.f, 0.f, 0.f);
    float dP = 1.f;
    if (cnt > 0) {
        int s0 = csr_src[e0];
        xsP = ld4f(xw, (size_t)s0 * 64 + sl * 4);
        dP = (float)deg[s0];
    }
    for (int t = 0; t < cnt; ++t) {
        float4 xs = xsP; float dv = dP;
        if (t + 1 < cnt) {                         // prefetch next edge
            int sn = csr_src[e0 + t + 1];
            xsP = ld4f(xw, (size_t)sn * 64 + sl * 4);
            dP = (float)deg[sn];
        }
        float p = xd.x * xs.x + xd.y * xs.y + xd.z * xs.z + xd.w * xs.w;
        float inner = gred16(p);                   // full 64-ch dot
        float gate = 1.f / (1.f + __expf(-rsqrtf(dv) * inner));
        float logit = inner * gate;
        float mn = fmaxf(m, logit);
        float sc = __expf(m - mn);                 // ==0 on first edge (m=-1e30)
        float w  = __expf(logit - mn);
        acc.x = acc.x * sc + w * xs.x;
        acc.y = acc.y * sc + w * xs.y;
        acc.z = acc.z * sc + w * xs.z;
        acc.w = acc.w * sc + w * xs.w;
        l = l * sc + w;
        m = mn;
    }
    float linv = 1.f / (l + 1e-16f);               // deg-0 dst: h = 0 (== ref)
    float4 hv = make_float4(leaky(acc.x * linv), leaky(acc.y * linv),
                            leaky(acc.z * linv), leaky(acc.w * linv));
    float4 xv = ld4f(xin, rb);
    // epilogue: accg = hv @ g.T, accl = xv @ lin.T (per-group 64x64 matmuls)
    float4 accg = make_float4(0.f, 0.f, 0.f, 0.f);
    float4 accl = make_float4(0.f, 0.f, 0.f, 0.f);
    int gbase = lane & 48;
    #pragma unroll
    for (int kk = 0; kk < 16; kk++) {
        int srcl = gbase | kk;
        float hb[4], xb[4];
        hb[0] = __shfl(hv.x, srcl, 64); xb[0] = __shfl(xv.x, srcl, 64);
        hb[1] = __shfl(hv.y, srcl, 64); xb[1] = __shfl(xv.y, srcl, 64);
        hb[2] = __shfl(hv.z, srcl, 64); xb[2] = __shfl(xv.z, srcl, 64);
        hb[3] = __shfl(hv.w, srcl, 64); xb[3] = __shfl(xv.w, srcl, 64);
        #pragma unroll
        for (int q = 0; q < 4; q++) {
            size_t wb = (size_t)(kk * 4 + q) * 64 + sl * 4;
            float4 g4 = ld4f(gT, wb);
            float4 l4 = ld4f(lT, wb);
            accg.x += hb[q] * g4.x; accg.y += hb[q] * g4.y;
            accg.z += hb[q] * g4.z; accg.w += hb[q] * g4.w;
            accl.x += xb[q] * l4.x; accl.y += xb[q] * l4.y;
            accl.z += xb[q] * l4.z; accl.w += xb[q] * l4.w;
        }
    }
    float4 lb4 = ldT4<T>(lb, sl * 4);
    float4 gb4 = ldT4<T>(gb, sl * 4);
    float4 id4 = ldT4<T>(id_emb, rb);
    float4 xn;
    xn.x = leaky(accg.x + gb4.x + leaky(accl.x + lb4.x) + id4.x);
    xn.y = leaky(accg.y + gb4.y + leaky(accl.y + lb4.y) + id4.y);
    xn.z = leaky(accg.z + gb4.z + leaky(accl.z + lb4.z) + id4.z);
    xn.w = leaky(accg.w + gb4.w + leaky(accl.w + lb4.w) + id4.w);
    *(float4*)(xnext + rb) = xn;
    stT4<T>(out, (size_t)i * 128 + off_out + sl * 4, xn);
}
__global__ void k_gat(const float* xw, const float* xin,
                      const int* csr_off, const int* csr_src, const int* deg,
                      const float* gT, const void* gb,
                      const float* lT, const void* lb, const void* id_emb,
                      float* xnext, void* out, int off_out, const int* mode) {
    if (*mode) gat_body<float>(xw, xin, csr_off, csr_src, deg, gT, gb, lT, lb,
                               id_emb, xnext, out, off_out);
    else       gat_body<bf16>(xw, xin, csr_off, csr_src, deg, gT, gb, lT, lb,
                              id_emb, xnext, out, off_out);
}

extern "C" void kernel_launch(void* const* d_in, const int* in_sizes, int n_in,
                              void* d_out, int out_size, void* d_ws, size_t ws_size,
                              hipStream_t stream) {
    const void* feat   = d_in[0];
    const void* uf     = d_in[1];
    const void* id_emb = d_in[2];
    const void* umw    = d_in[3];
    const void* umb    = d_in[4];
    const void* gat1   = d_in[5];
    const void* lin1b  = d_in[7];
    const void* g1b    = d_in[9];
    const void* gat2   = d_in[10];
    const void* lin2b  = d_in[12];
    const void* g2b    = d_in[14];
    const int*  ei     = (const int*)d_in[15];
    const int* src = ei;
    const int* dst = ei + NE;

    // workspace layout (~82.6 MB)
    int*      mode   = (int*)d_ws;                       // 16 B slot
    int*      deg    = (int*)((char*)d_ws + 16);         // NN
    int*      cnt    = deg + NN;                         // NN (adjacent: one memset)
    int*      cursor = cnt + NN;                         // NN
    int*      csr_off = cursor + NN;                     // NN+16
    int*      tsum   = csr_off + NN + 16;                // 128
    int*      toff   = tsum + 128;                       // 128
    float*    umwT   = (float*)(toff + 128);             // 8192
    float*    wT     = umwT + 8192;                      // 4 x 4096
    int*      csr_src = (int*)(wT + 4 * 4096);           // NE
    float*    buf0   = (float*)(csr_src + NE);           // x     (25.6 MB)
    float*    buf1   = buf0 + (size_t)NN * 64;           // xw    (25.6 MB)
    float*    buf2   = buf1 + (size_t)NN * 64;           // x1/x2 (25.6 MB)

    k_detect<<<1, 256, 0, stream>>>((const unsigned short*)feat, mode);
    k_prep_w<<<96, 256, 0, stream>>>(umw, d_in[6], d_in[8], d_in[11], d_in[13],
                                     umwT, wT, mode);
    hipMemsetAsync(deg, 0, 2 * NN * 4, stream);          // deg + cnt (adjacent)
    k_deg<<<(NE + 255) / 256, 256, 0, stream>>>(src, dst, deg, cnt);
    k_scan_sum<<<SCAN_TILES, SCAN_T, 0, stream>>>(cnt, tsum);
    k_scan_tiles<<<1, SCAN_T, 0, stream>>>(tsum, toff);
    k_scan_out<<<SCAN_TILES, SCAN_T, 0, stream>>>(cnt, toff, csr_off, cursor);
    k_scatter<<<(NE + 255) / 256, 256, 0, stream>>>(src, dst, cursor, csr_src);
    k_prep_items<<<(N_ITEM + 3) / 4, 256, 0, stream>>>(feat, buf0, mode);
    k_prep_users<<<(N_USER + 3) / 4, 256, 0, stream>>>(uf, umwT, umb, buf0, mode);

    const float* lT1 = wT;
    const float* gT1 = wT + 4096;
    const float* lT2 = wT + 8192;
    const float* gT2 = wT + 12288;

    // 16 nodes per block
    int gat_blocks = (NN + 15) / 16;   // 6250

    // hop 1: x(buf0) -> xw1(buf1) -> x1(buf2), out cols 0..63
    k_xw<<<gat_blocks, 256, 0, stream>>>(buf0, gat1, buf1, mode);
    k_gat<<<gat_blocks, 256, 0, stream>>>(buf1, buf0, csr_off, csr_src, deg,
                                          gT1, g1b, lT1, lin1b, id_emb,
                                          buf2, d_out, 0, mode);
    // hop 2: x1(buf2) -> xw2(buf1) -> x2(buf0), out cols 64..127
    k_xw<<<gat_blocks, 256, 0, stream>>>(buf2, gat2, buf1, mode);
    k_gat<<<gat_blocks, 256, 0, stream>>>(buf1, buf2, csr_off, csr_src, deg,
                                          gT2, g2b, lT2, lin2b, id_emb,
                                          buf0, d_out, 64, mode);
}

// Round 8
// 680.076 us; speedup vs baseline: 3.3559x; 1.0266x over previous
//
#include <hip/hip_runtime.h>
#include <hip/hip_bf16.h>

// Problem constants (fixed by the reference's setup_inputs)
#define N_ITEM 80000
#define N_USER 20000
#define NN     100000   // N_ITEM + N_USER
#define NE     1000000  // edges
#define SCAN_T 1024
#define SCAN_TILES ((NN + SCAN_T - 1) / SCAN_T)   // 98

typedef __hip_bfloat16 bf16;

__device__ __forceinline__ float b2f(bf16 v) { return __bfloat162float(v); }
__device__ __forceinline__ bf16  f2b(float v) { return __float2bfloat16(v); }
__device__ __forceinline__ float bits2f(unsigned short h) {
    return __uint_as_float(((unsigned)h) << 16);
}
__device__ __forceinline__ float leaky(float v) { return v >= 0.f ? v : 0.01f * v; }

// dtype-adaptive scalar load
template<typename T>
__device__ __forceinline__ float ldT(const void* p, size_t i);
template<> __device__ __forceinline__ float ldT<float>(const void* p, size_t i) {
    return ((const float*)p)[i];
}
template<> __device__ __forceinline__ float ldT<bf16>(const void* p, size_t i) {
    return b2f(((const bf16*)p)[i]);
}
// dtype-adaptive float4 load/store (i multiple of 4)
template<typename T>
__device__ __forceinline__ float4 ldT4(const void* p, size_t i);
template<> __device__ __forceinline__ float4 ldT4<float>(const void* p, size_t i) {
    return *(const float4*)((const float*)p + i);
}
template<> __device__ __forceinline__ float4 ldT4<bf16>(const void* p, size_t i) {
    ushort4 u = *(const ushort4*)((const unsigned short*)p + i);
    return make_float4(bits2f(u.x), bits2f(u.y), bits2f(u.z), bits2f(u.w));
}
template<typename T>
__device__ __forceinline__ void stT4(void* p, size_t i, float4 v);
template<> __device__ __forceinline__ void stT4<float>(void* p, size_t i, float4 v) {
    *(float4*)((float*)p + i) = v;
}
template<> __device__ __forceinline__ void stT4<bf16>(void* p, size_t i, float4 v) {
    bf16 b0 = f2b(v.x), b1 = f2b(v.y), b2 = f2b(v.z), b3 = f2b(v.w);
    ushort4 u = make_ushort4(*(unsigned short*)&b0, *(unsigned short*)&b1,
                             *(unsigned short*)&b2, *(unsigned short*)&b3);
    *(ushort4*)((unsigned short*)p + i) = u;
}
__device__ __forceinline__ float4 ld4f(const float* p, size_t i) {
    return *(const float4*)(p + i);
}
// bf16 xw-table load/store (ushort bits)
__device__ __forceinline__ float4 ld4b(const unsigned short* p, size_t i) {
    ushort4 u = *(const ushort4*)(p + i);
    return make_float4(bits2f(u.x), bits2f(u.y), bits2f(u.z), bits2f(u.w));
}
__device__ __forceinline__ void st4b(unsigned short* p, size_t i, float4 v) {
    bf16 b0 = f2b(v.x), b1 = f2b(v.y), b2 = f2b(v.z), b3 = f2b(v.w);
    ushort4 u = make_ushort4(*(unsigned short*)&b0, *(unsigned short*)&b1,
                             *(unsigned short*)&b2, *(unsigned short*)&b3);
    *(ushort4*)(p + i) = u;
}

// full 64-lane wave sum (float)
__device__ __forceinline__ float wred(float v) {
    for (int o = 32; o; o >>= 1) v += __shfl_xor(v, o, 64);
    return v;
}
// 16-lane group sum
__device__ __forceinline__ float gred16(float v) {
    for (int o = 8; o; o >>= 1) v += __shfl_xor(v, o, 64);
    return v;
}
// 64-lane inclusive scan (int)
__device__ __forceinline__ int wscan(int v, int lane) {
    for (int o = 1; o < 64; o <<= 1) {
        int t = __shfl_up(v, o, 64);
        v += (lane >= o) ? t : 0;
    }
    return v;
}

// ---- storage-dtype detection (bf16 vs f32 harness buffers) ----
__global__ void k_detect(const unsigned short* __restrict__ w, int* __restrict__ mode) {
    __shared__ int cnt[256];
    int bad = 0;
    for (int i = threadIdx.x; i < 4096; i += 256) {
        unsigned e = (w[i] >> 7) & 0xFFu;
        bad += (e == 0u || e == 0xFFu) ? 1 : 0;
    }
    cnt[threadIdx.x] = bad;
    __syncthreads();
    if (threadIdx.x == 0) {
        int t = 0;
        for (int k = 0; k < 256; k++) t += cnt[k];
        mode[0] = (t > 0) ? 1 : 0;   // 1 = float32 storage, 0 = bf16 storage
    }
}

// ---- transpose + f32-promote row-major weights ----
__global__ void k_prep_w(const void* umw, const void* lw1, const void* gw1,
                         const void* lw2, const void* gw2,
                         float* umwT, float* wT, const int* mode) {
    int t = blockIdx.x * 256 + threadIdx.x;   // 0 .. 24575
    bool f32m = (*mode != 0);
    if (t < 8192) {
        int j = t >> 7, k = t & 127;
        float v = f32m ? ldT<float>(umw, t) : ldT<bf16>(umw, t);
        umwT[k * 64 + j] = v;
    } else {
        int u = t - 8192;
        int m = u >> 12;          // 0..3
        int r = u & 4095;
        int j = r >> 6, k = r & 63;
        const void* srcp = (m == 0) ? lw1 : (m == 1) ? gw1 : (m == 2) ? lw2 : gw2;
        float v = f32m ? ldT<float>(srcp, r) : ldT<bf16>(srcp, r);
        wT[m * 4096 + k * 64 + j] = v;
    }
}

// ---- degree counts: out-degree over src (gate) + in-degree over dst (CSR) ----
__global__ void k_deg(const int* __restrict__ src, const int* __restrict__ dst,
                      int* __restrict__ deg, int* __restrict__ cnt) {
    int e = blockIdx.x * blockDim.x + threadIdx.x;
    if (e < NE) {
        atomicAdd(&deg[src[e]], 1);
        atomicAdd(&cnt[dst[e]], 1);
    }
}

// ---- dinv[i] = rsqrt(deg[i]) precompute ----
__global__ void k_dinv(const int* __restrict__ deg, float* __restrict__ dinv) {
    int i = blockIdx.x * blockDim.x + threadIdx.x;
    if (i < NN) dinv[i] = rsqrtf((float)max(deg[i], 1));
}

// ---- parallel scan, pass 1: per-tile sums ----
__global__ void k_scan_sum(const int* __restrict__ cnt, int* __restrict__ tsum) {
    __shared__ int wsum[16];
    int i = blockIdx.x * SCAN_T + threadIdx.x;
    int lane = threadIdx.x & 63, wid = threadIdx.x >> 6;
    int v = (i < NN) ? cnt[i] : 0;
    float s = wred((float)v);               // exact: counts < 2^24
    if (lane == 0) wsum[wid] = (int)s;
    __syncthreads();
    if (threadIdx.x == 0) {
        int t = 0;
        #pragma unroll
        for (int k = 0; k < 16; k++) t += wsum[k];
        tsum[blockIdx.x] = t;
    }
}

// ---- pass 2: exclusive scan of the tile sums (1 block) ----
__global__ void k_scan_tiles(const int* __restrict__ tsum, int* __restrict__ toff) {
    __shared__ int wsum[16];
    int lane = threadIdx.x & 63, wid = threadIdx.x >> 6;
    int v = (threadIdx.x < SCAN_TILES) ? tsum[threadIdx.x] : 0;
    int inc = wscan(v, lane);
    if (lane == 63) wsum[wid] = inc;
    __syncthreads();
    if (wid == 0) {
        int ws = (lane < 16) ? wsum[lane] : 0;
        int wi = wscan(ws, lane);
        if (lane < 16) wsum[lane] = wi - ws;   // exclusive wave offsets
    }
    __syncthreads();
    if (threadIdx.x < SCAN_TILES) toff[threadIdx.x] = inc - v + wsum[wid];
}

// ---- pass 3: block-local exclusive scan + tile offset -> csr_off, cursor ----
__global__ void k_scan_out(const int* __restrict__ cnt, const int* __restrict__ toff,
                           int* __restrict__ csr_off, int* __restrict__ cursor) {
    __shared__ int wsum[16];
    int i = blockIdx.x * SCAN_T + threadIdx.x;
    int lane = threadIdx.x & 63, wid = threadIdx.x >> 6;
    int v = (i < NN) ? cnt[i] : 0;
    int inc = wscan(v, lane);
    if (lane == 63) wsum[wid] = inc;
    __syncthreads();
    if (wid == 0) {
        int ws = (lane < 16) ? wsum[lane] : 0;
        int wi = wscan(ws, lane);
        if (lane < 16) wsum[lane] = wi - ws;
    }
    __syncthreads();
    int excl = inc - v + wsum[wid] + toff[blockIdx.x];
    if (i < NN) { csr_off[i] = excl; cursor[i] = excl; }
    if (i == NN - 1) csr_off[NN] = excl + v;   // == NE
}

// ---- scatter edges into dst-sorted CSR ----
__global__ void k_scatter(const int* __restrict__ src, const int* __restrict__ dst,
                          int* __restrict__ cursor, int* __restrict__ csr_src) {
    int e = blockIdx.x * blockDim.x + threadIdx.x;
    if (e < NE) {
        int pos = atomicAdd(&cursor[dst[e]], 1);
        csr_src[pos] = src[e];
    }
}

// ---- item rows: normalize(features) -> x[0:80000] ----
template<typename T>
__device__ __forceinline__ void prep_items_body(const void* feat, float* x) {
    int i = blockIdx.x * 4 + (threadIdx.x >> 6);
    int j = threadIdx.x & 63;
    if (i >= N_ITEM) return;
    float v = ldT<T>(feat, (size_t)i * 64 + j);
    float ss = wred(v * v);
    float inv = 1.f / fmaxf(sqrtf(ss), 1e-12f);
    x[(size_t)i * 64 + j] = v * inv;
}
__global__ void k_prep_items(const void* feat, float* x, const int* mode) {
    if (*mode) prep_items_body<float>(feat, x);
    else       prep_items_body<bf16>(feat, x);
}

// ---- user rows: normalize(tanh(uf @ W.T + b)) via transposed f32 weights ----
template<typename T>
__device__ __forceinline__ void prep_users_body(const void* uf, const float* wT,
                                                const void* b, float* x) {
    int u = blockIdx.x * 4 + (threadIdx.x >> 6);
    int j = threadIdx.x & 63;
    if (u >= N_USER) return;
    size_t ub = (size_t)u * 128;
    float acc = ldT<T>(b, j);
    #pragma unroll 8
    for (int k = 0; k < 128; k++)
        acc += ldT<T>(uf, ub + k) * wT[k * 64 + j];
    float v = tanhf(acc);
    float ss = wred(v * v);
    float inv = 1.f / fmaxf(sqrtf(ss), 1e-12f);
    x[(size_t)(N_ITEM + u) * 64 + j] = v * inv;
}
__global__ void k_prep_users(const void* uf, const float* wT, const void* b,
                             float* x, const int* mode) {
    if (*mode) prep_users_body<float>(uf, wT, b, x);
    else       prep_users_body<bf16>(uf, wT, b, x);
}

// ---- xw = xin @ W -> bf16 table, 16 lanes/node x float4 ----
template<typename T>
__device__ __forceinline__ void xw_body(const float* __restrict__ xin,
                                        const void* __restrict__ W,
                                        unsigned short* __restrict__ xw) {
    int lane = threadIdx.x & 63, wid = threadIdx.x >> 6;
    int sl = lane & 15;
    int i = blockIdx.x * 16 + (wid << 2) + (lane >> 4);
    if (i >= NN) return;
    size_t rb = (size_t)i * 64 + sl * 4;
    float4 xv = ld4f(xin, rb);
    float4 acc = make_float4(0.f, 0.f, 0.f, 0.f);
    int gbase = lane & 48;
    #pragma unroll
    for (int kk = 0; kk < 16; kk++) {
        int srcl = gbase | kk;
        float xb[4];
        xb[0] = __shfl(xv.x, srcl, 64);
        xb[1] = __shfl(xv.y, srcl, 64);
        xb[2] = __shfl(xv.z, srcl, 64);
        xb[3] = __shfl(xv.w, srcl, 64);
        #pragma unroll
        for (int q = 0; q < 4; q++) {
            float4 w4 = ldT4<T>(W, (size_t)(kk * 4 + q) * 64 + sl * 4);
            acc.x += xb[q] * w4.x; acc.y += xb[q] * w4.y;
            acc.z += xb[q] * w4.z; acc.w += xb[q] * w4.w;
        }
    }
    st4b(xw, rb, acc);               // bf16 table: halves gather bytes in k_gat
}
__global__ void k_xw(const float* xin, const void* W, unsigned short* xw,
                     const int* mode) {
    if (*mode) xw_body<float>(xin, W, xw);
    else       xw_body<bf16>(xin, W, xw);
}

// ---- fused GAT layer: 16 lanes/node x float4, bf16 gathers, 2-deep prefetch ----
template<typename T>
__device__ __forceinline__ void gat_body(const unsigned short* __restrict__ xw,
                                         const float* __restrict__ xin,
                                         const int* __restrict__ csr_off,
                                         const int* __restrict__ csr_src,
                                         const float* __restrict__ dinv,
                                         const float* __restrict__ gT, const void* gb,
                                         const float* __restrict__ lT, const void* lb,
                                         const void* id_emb,
                                         float* __restrict__ xnext, void* out,
                                         int off_out) {
    int lane = threadIdx.x & 63, wid = threadIdx.x >> 6;
    int sl = lane & 15;
    int i = blockIdx.x * 16 + (wid << 2) + (lane >> 4);
    if (i >= NN) return;
    size_t rb = (size_t)i * 64 + sl * 4;
    float4 xd = ld4b(xw, rb);
    int e0 = csr_off[i], e1 = csr_off[i + 1];
    int cnt = e1 - e0;
    float m = -1e30f, l = 0.f;
    float4 acc = make_float4(0.f, 0.f, 0.f, 0.f);
    // 2-deep software pipeline over the segment's gathers
    float4 xsA = make_float4(0.f, 0.f, 0.f, 0.f), xsB = xsA;
    float dA = 1.f, dB = 1.f;
    if (cnt > 0) {
        int s0 = csr_src[e0];
        xsA = ld4b(xw, (size_t)s0 * 64 + sl * 4);
        dA = dinv[s0];
    }
    if (cnt > 1) {
        int s1 = csr_src[e0 + 1];
        xsB = ld4b(xw, (size_t)s1 * 64 + sl * 4);
        dB = dinv[s1];
    }
    for (int t = 0; t < cnt; ++t) {
        float4 xs = xsA; float dv = dA;
        xsA = xsB; dA = dB;
        if (t + 2 < cnt) {
            int sn = csr_src[e0 + t + 2];
            xsB = ld4b(xw, (size_t)sn * 64 + sl * 4);
            dB = dinv[sn];
        }
        float p = xd.x * xs.x + xd.y * xs.y + xd.z * xs.z + xd.w * xs.w;
        float inner = gred16(p);                   // full 64-ch dot
        float gate = 1.f / (1.f + __expf(-dv * inner));
        float logit = inner * gate;
        float mn = fmaxf(m, logit);
        float sc = __expf(m - mn);                 // ==0 on first edge (m=-1e30)
        float w  = __expf(logit - mn);
        acc.x = acc.x * sc + w * xs.x;
        acc.y = acc.y * sc + w * xs.y;
        acc.z = acc.z * sc + w * xs.z;
        acc.w = acc.w * sc + w * xs.w;
        l = l * sc + w;
        m = mn;
    }
    float linv = 1.f / (l + 1e-16f);               // deg-0 dst: h = 0 (== ref)
    float4 hv = make_float4(leaky(acc.x * linv), leaky(acc.y * linv),
                            leaky(acc.z * linv), leaky(acc.w * linv));
    float4 xv = ld4f(xin, rb);
    // epilogue: accg = hv @ g.T, accl = xv @ lin.T (per-group 64x64 matmuls)
    float4 accg = make_float4(0.f, 0.f, 0.f, 0.f);
    float4 accl = make_float4(0.f, 0.f, 0.f, 0.f);
    int gbase = lane & 48;
    #pragma unroll
    for (int kk = 0; kk < 16; kk++) {
        int srcl = gbase | kk;
        float hb[4], xb[4];
        hb[0] = __shfl(hv.x, srcl, 64); xb[0] = __shfl(xv.x, srcl, 64);
        hb[1] = __shfl(hv.y, srcl, 64); xb[1] = __shfl(xv.y, srcl, 64);
        hb[2] = __shfl(hv.z, srcl, 64); xb[2] = __shfl(xv.z, srcl, 64);
        hb[3] = __shfl(hv.w, srcl, 64); xb[3] = __shfl(xv.w, srcl, 64);
        #pragma unroll
        for (int q = 0; q < 4; q++) {
            size_t wb = (size_t)(kk * 4 + q) * 64 + sl * 4;
            float4 g4 = ld4f(gT, wb);
            float4 l4 = ld4f(lT, wb);
            accg.x += hb[q] * g4.x; accg.y += hb[q] * g4.y;
            accg.z += hb[q] * g4.z; accg.w += hb[q] * g4.w;
            accl.x += xb[q] * l4.x; accl.y += xb[q] * l4.y;
            accl.z += xb[q] * l4.z; accl.w += xb[q] * l4.w;
        }
    }
    float4 lb4 = ldT4<T>(lb, sl * 4);
    float4 gb4 = ldT4<T>(gb, sl * 4);
    float4 id4 = ldT4<T>(id_emb, rb);
    float4 xn;
    xn.x = leaky(accg.x + gb4.x + leaky(accl.x + lb4.x) + id4.x);
    xn.y = leaky(accg.y + gb4.y + leaky(accl.y + lb4.y) + id4.y);
    xn.z = leaky(accg.z + gb4.z + leaky(accl.z + lb4.z) + id4.z);
    xn.w = leaky(accg.w + gb4.w + leaky(accl.w + lb4.w) + id4.w);
    *(float4*)(xnext + rb) = xn;
    stT4<T>(out, (size_t)i * 128 + off_out + sl * 4, xn);
}
__global__ void k_gat(const unsigned short* xw, const float* xin,
                      const int* csr_off, const int* csr_src, const float* dinv,
                      const float* gT, const void* gb,
                      const float* lT, const void* lb, const void* id_emb,
                      float* xnext, void* out, int off_out, const int* mode) {
    if (*mode) gat_body<float>(xw, xin, csr_off, csr_src, dinv, gT, gb, lT, lb,
                               id_emb, xnext, out, off_out);
    else       gat_body<bf16>(xw, xin, csr_off, csr_src, dinv, gT, gb, lT, lb,
                              id_emb, xnext, out, off_out);
}

extern "C" void kernel_launch(void* const* d_in, const int* in_sizes, int n_in,
                              void* d_out, int out_size, void* d_ws, size_t ws_size,
                              hipStream_t stream) {
    const void* feat   = d_in[0];
    const void* uf     = d_in[1];
    const void* id_emb = d_in[2];
    const void* umw    = d_in[3];
    const void* umb    = d_in[4];
    const void* gat1   = d_in[5];
    const void* lin1b  = d_in[7];
    const void* g1b    = d_in[9];
    const void* gat2   = d_in[10];
    const void* lin2b  = d_in[12];
    const void* g2b    = d_in[14];
    const int*  ei     = (const int*)d_in[15];
    const int* src = ei;
    const int* dst = ei + NE;

    // workspace layout (~70 MB)
    int*      mode   = (int*)d_ws;                       // 16 B slot
    int*      deg    = (int*)((char*)d_ws + 16);         // NN
    int*      cnt    = deg + NN;                         // NN (adjacent: one memset)
    int*      cursor = cnt + NN;                         // NN
    int*      csr_off = cursor + NN;                     // NN+16
    int*      tsum   = csr_off + NN + 16;                // 128
    int*      toff   = tsum + 128;                       // 128
    float*    dinv   = (float*)(toff + 128);             // NN
    float*    umwT   = dinv + NN;                        // 8192
    float*    wT     = umwT + 8192;                      // 4 x 4096
    int*      csr_src = (int*)(wT + 4 * 4096);           // NE
    float*    buf0   = (float*)(csr_src + NE);           // x     (25.6 MB f32)
    float*    buf2   = buf0 + (size_t)NN * 64;           // x1/x2 (25.6 MB f32)
    unsigned short* xwb = (unsigned short*)(buf2 + (size_t)NN * 64); // 12.8 MB bf16

    k_detect<<<1, 256, 0, stream>>>((const unsigned short*)feat, mode);
    k_prep_w<<<96, 256, 0, stream>>>(umw, d_in[6], d_in[8], d_in[11], d_in[13],
                                     umwT, wT, mode);
    hipMemsetAsync(deg, 0, 2 * NN * 4, stream);          // deg + cnt (adjacent)
    k_deg<<<(NE + 255) / 256, 256, 0, stream>>>(src, dst, deg, cnt);
    k_dinv<<<(NN + 255) / 256, 256, 0, stream>>>(deg, dinv);
    k_scan_sum<<<SCAN_TILES, SCAN_T, 0, stream>>>(cnt, tsum);
    k_scan_tiles<<<1, SCAN_T, 0, stream>>>(tsum, toff);
    k_scan_out<<<SCAN_TILES, SCAN_T, 0, stream>>>(cnt, toff, csr_off, cursor);
    k_scatter<<<(NE + 255) / 256, 256, 0, stream>>>(src, dst, cursor, csr_src);
    k_prep_items<<<(N_ITEM + 3) / 4, 256, 0, stream>>>(feat, buf0, mode);
    k_prep_users<<<(N_USER + 3) / 4, 256, 0, stream>>>(uf, umwT, umb, buf0, mode);

    const float* lT1 = wT;
    const float* gT1 = wT + 4096;
    const float* lT2 = wT + 8192;
    const float* gT2 = wT + 12288;

    int gat_blocks = (NN + 15) / 16;   // 6250, 16 nodes/block

    // hop 1: x(buf0) -> xw(bf16) -> x1(buf2), out cols 0..63
    k_xw<<<gat_blocks, 256, 0, stream>>>(buf0, gat1, xwb, mode);
    k_gat<<<gat_blocks, 256, 0, stream>>>(xwb, buf0, csr_off, csr_src, dinv,
                                          gT1, g1b, lT1, lin1b, id_emb,
                                          buf2, d_out, 0, mode);
    // hop 2: x1(buf2) -> xw(bf16) -> x2(buf0), out cols 64..127
    k_xw<<<gat_blocks, 256, 0, stream>>>(buf2, gat2, xwb, mode);
    k_gat<<<gat_blocks, 256, 0, stream>>>(xwb, buf2, csr_off, csr_src, dinv,
                                          gT2, g2b, lT2, lin2b, id_emb,
                                          buf0, d_out, 64, mode);
}